// Round 4
// baseline (3297.188 us; speedup 1.0000x reference)
//
#include <hip/hip_runtime.h>
#include <hip/hip_bf16.h>

typedef __attribute__((ext_vector_type(8))) __bf16 bf16x8;
typedef __attribute__((ext_vector_type(4))) float  f32x4;

#define SCOPE_AGENT __HIP_MEMORY_SCOPE_AGENT

static __device__ __forceinline__ f32x4 mfma16(bf16x8 a, bf16x8 b, f32x4 c) {
    return __builtin_amdgcn_mfma_f32_16x16x32_bf16(a, b, c, 0, 0, 0);
}
static __device__ __forceinline__ float sigm(float x)  { return 1.0f / (1.0f + __expf(-x)); }
static __device__ __forceinline__ float tanh_(float x) { return 1.0f - 2.0f / (__expf(2.0f * x) + 1.0f); }

static __device__ __forceinline__ bf16x8 cvt8(const float* __restrict__ p) {
    const float4* q = (const float4*)p;
    float4 a = q[0], b = q[1];
    bf16x8 r;
    r[0] = (__bf16)a.x; r[1] = (__bf16)a.y; r[2] = (__bf16)a.z; r[3] = (__bf16)a.w;
    r[4] = (__bf16)b.x; r[5] = (__bf16)b.y; r[6] = (__bf16)b.z; r[7] = (__bf16)b.w;
    return r;
}
static __device__ __forceinline__ unsigned int ld_rlx(const unsigned int* p) {
    return __hip_atomic_load((unsigned int*)p, __ATOMIC_RELAXED, SCOPE_AGENT);
}
union g4u { unsigned long long q; __bf16 h[4]; };

// ---------------------------------------------------------------------------
// ws layout (bytes):
//   0        flags (1024, zeroed): pa_done[l*16+bid] @0..320; z_done @ u32[128+l*2+dir]
//   1024     zbuf  [2][64][512] bf16 = 131072   (zbuf0 @1024 survives -> fc)
//   132096   Gx_g  [2][64][1024] bf16 = 262144  (dead after lstm)
//   66560    convWb overlay (554688) over zbuf1+Gx, written after lstm -> 621248
//   621248   arenaA (20,574,208)
//   21195456 arenaB (41,148,416)  [lstm bf16 weights @0..16.7MB, dead after lstm;
//                                  fcWb @ +2,097,152 B, dead after fc]
// total 62,343,872 B (<= round-3 footprint 62,443,776)
// ---------------------------------------------------------------------------
#define ZBUF_OFF   1024
#define GX_OFF     132096
#define CONVW_OFF  66560
#define ARENA_A    621248
#define ARENA_B    21195456
// lstm weight element offsets in arenaB (bf16 elems)
#define O_WIH0  0            // [2][1024][768]
#define O_WIHL  1572864      // [4][2][1024][512]
#define O_WHHP  5767168      // [10][32768][8] permuted

// ---------------------------------------------------------------------------
// one-time f32->bf16: Wih plain copy
// ---------------------------------------------------------------------------
__global__ __launch_bounds__(256) void precvt_lstm(
    const float* __restrict__ Wih0, const float* __restrict__ WihL,
    __bf16* __restrict__ out)
{
    int f = (blockIdx.x * 256 + threadIdx.x) * 4;
    const float* src; int off;
    if (f < 1572864) { src = Wih0; off = f; }
    else             { src = WihL; off = f - 1572864; }
    float4 v = *(const float4*)(src + off);
    g4u u;
    u.h[0] = (__bf16)v.x; u.h[1] = (__bf16)v.y; u.h[2] = (__bf16)v.z; u.h[3] = (__bf16)v.w;
    *(unsigned long long*)(out + f) = u.q;
}

// ---------------------------------------------------------------------------
// one-time: Whh -> fragment-order permuted bf16 (coalesced wf loads in rec).
// unit u: dl=u>>15; local=u&32767: lane=local&63, kc=(local>>6)&7, mi=local>>9
// m=mi*16+(lane&15); r=(m&3)*256+(m>>2); col=kc*32+(lane>>4)*8
// ---------------------------------------------------------------------------
__global__ __launch_bounds__(256) void precvt_whh(
    const float* __restrict__ Whh0, const float* __restrict__ WhhL,
    __bf16* __restrict__ WhhP)
{
    int u = blockIdx.x * 256 + threadIdx.x;   // 0..327679
    int dl = u >> 15;
    int local = u & 32767;
    int lane = local & 63;
    int kc = (local >> 6) & 7;
    int mi = local >> 9;
    int m = mi * 16 + (lane & 15);
    int r = (m & 3) * 256 + (m >> 2);
    int col = kc * 32 + (lane >> 4) * 8;
    const float* src = (dl < 2) ? (Whh0 + (size_t)dl * 262144)
                                : (WhhL + (size_t)(dl - 2) * 262144);
    const float4* q = (const float4*)(src + (size_t)r * 256 + col);
    float4 a = q[0], b = q[1];
    g4u u0, u1;
    u0.h[0] = (__bf16)a.x; u0.h[1] = (__bf16)a.y; u0.h[2] = (__bf16)a.z; u0.h[3] = (__bf16)a.w;
    u1.h[0] = (__bf16)b.x; u1.h[1] = (__bf16)b.y; u1.h[2] = (__bf16)b.z; u1.h[3] = (__bf16)b.w;
    unsigned long long* dst = (unsigned long long*)(WhhP + (size_t)u * 8);
    dst[0] = u0.q; dst[1] = u1.q;
}

// decoder weights f32->bf16 (after lstm; convWb overlays dead lstm buffers)
__global__ __launch_bounds__(256) void precvt_dec(
    const float* __restrict__ fcW, const float* __restrict__ c3W,
    const float* __restrict__ c2W, const float* __restrict__ c1W,
    const float* __restrict__ c0W, const float* __restrict__ hW,
    __bf16* __restrict__ fcWb, __bf16* __restrict__ convWb)
{
    int f = (blockIdx.x * 256 + threadIdx.x) * 4;
    if (f >= 1588064) return;
    const float* src; int off; __bf16* dst; int doff;
    if (f < 1310720) { src = fcW; off = f; dst = fcWb; doff = f; }
    else {
        int g = f - 1310720; dst = convWb; doff = g;
        if (g < 147456)      { src = c3W; off = g; }
        else if (g < 221184) { src = c2W; off = g - 147456; }
        else if (g < 258048) { src = c1W; off = g - 221184; }
        else if (g < 276480) { src = c0W; off = g - 258048; }
        else                 { src = hW;  off = g - 276480; }
    }
    float4 v = *(const float4*)(src + off);
    g4u u;
    u.h[0] = (__bf16)v.x; u.h[1] = (__bf16)v.y; u.h[2] = (__bf16)v.z; u.h[3] = (__bf16)v.w;
    *(unsigned long long*)(dst + doff) = u.q;
}

// ---------------------------------------------------------------------------
// Fused LSTM, grid = 18 x 1024:
//  bid 0..15 : Phase-A WGs (dir=bid>>3, sub=bid&7; 128 gate-rows x 64 t per WG)
//              per layer: wait z_done[l-1] -> Gx = Wih@x + b -> set pa_done[l]
//  bid 16,17 : recurrence WGs (dir=bid-16). Whole direction on ONE CU:
//              Whh register-resident (wf[4][8] per wave, from permuted WhhP),
//              h in LDS ping-pong, Gx read per-step from global (prefetched
//              ahead of the 512-MFMA block). NO cross-CU ops in the step loop.
// m-index convention everywhere: m = cell*4 + gate; weight row r = gate*256+cell.
// ---------------------------------------------------------------------------
__global__ __launch_bounds__(1024) void lstm_fused(
    const float* __restrict__ audio,
    const __bf16* __restrict__ WihB,    // plain bf16 Wih (l0 then l1-4)
    const __bf16* __restrict__ WhhP,    // permuted bf16 Whh
    const float* __restrict__ b0, const float* __restrict__ bL,
    unsigned short* __restrict__ Gx_g,  // [2][64][1024] bf16 bits
    unsigned int* __restrict__ flags,
    unsigned short* __restrict__ zbuf)  // [2][64][512] bf16 bits
{
    const int bid = blockIdx.x;
    const int tid = threadIdx.x;
    const int wave = tid >> 6, lane = tid & 63, ln = lane & 15, quad = lane >> 4;
    __shared__ __align__(16) unsigned short hbuf[2][256];

    if (bid < 16) {
        // ---------------- Phase A ----------------
        const int dir = bid >> 3, sub = bid & 7;
        const int mt = wave >> 1, ntb = (wave & 1) * 2;
        for (int l = 0; l < 5; ++l) {
            if (l > 0) {
                if (tid == 0) {
                    while (ld_rlx(&flags[128 + (l - 1) * 2 + 0]) == 0) __builtin_amdgcn_s_sleep(2);
                    while (ld_rlx(&flags[128 + (l - 1) * 2 + 1]) == 0) __builtin_amdgcn_s_sleep(2);
                    (void)__hip_atomic_load(&flags[128 + (l - 1) * 2], __ATOMIC_ACQUIRE, SCOPE_AGENT);
                }
                __syncthreads();
            }
            const int Din = l ? 512 : 768;
            const __bf16* Wih_l = l ? (WihB + O_WIHL + (size_t)((l - 1) * 2 + dir) * 524288)
                                    : (WihB + (size_t)dir * 786432);
            const float* b_l = l ? (bL + (size_t)((l - 1) * 2 + dir) * 1024)
                                 : (b0 + (size_t)dir * 1024);
            const __bf16* zp = (const __bf16*)(zbuf + (size_t)((l - 1) & 1) * 32768);

            f32x4 acc[2];
            acc[0] = (f32x4){0.f, 0.f, 0.f, 0.f};
            acc[1] = (f32x4){0.f, 0.f, 0.f, 0.f};
            const int m_a = sub * 128 + mt * 16 + ln;
            const int r_a = (m_a & 3) * 256 + (m_a >> 2);
            const int Kc = Din >> 5;
            for (int kc = 0; kc < Kc; ++kc) {
                const int k0 = kc * 32 + quad * 8;
                bf16x8 afr = *(const bf16x8*)(Wih_l + (size_t)r_a * Din + k0);
                #pragma unroll
                for (int e = 0; e < 2; ++e) {
                    const int t = (ntb + e) * 16 + ln;
                    bf16x8 bfr = l ? *(const bf16x8*)(zp + (size_t)t * 512 + k0)
                                   : cvt8(audio + (size_t)t * 768 + k0);
                    acc[e] = mfma16(afr, bfr, acc[e]);
                }
            }
            #pragma unroll
            for (int reg = 0; reg < 4; ++reg) {
                const int m_row = sub * 128 + mt * 16 + quad * 4 + reg;
                const int r_row = (m_row & 3) * 256 + (m_row >> 2);
                const float bv = b_l[r_row];
                #pragma unroll
                for (int e = 0; e < 2; ++e) {
                    const int t = (ntb + e) * 16 + ln;
                    __bf16 v = (__bf16)(acc[e][reg] + bv);
                    Gx_g[(size_t)dir * 65536 + t * 1024 + m_row] =
                        __builtin_bit_cast(unsigned short, v);
                }
            }
            __syncthreads();
            if (tid == 0) {
                __threadfence();
                __hip_atomic_store(&flags[l * 16 + bid], 1u, __ATOMIC_RELEASE, SCOPE_AGENT);
            }
        }
    } else {
        // ---------------- recurrence (one WG = one direction = one CU) ------
        const int dir = bid - 16;
        const unsigned short* Gx_d = Gx_g + (size_t)dir * 65536;
        for (int l = 0; l < 5; ++l) {
            const int dl = l * 2 + dir;
            // issue Whh fragment loads first (overlap with Phase-A wait)
            bf16x8 wf[4][8];
            const __bf16* wb = WhhP + (size_t)dl * 262144;
            #pragma unroll
            for (int i = 0; i < 4; ++i)
                #pragma unroll
                for (int kc = 0; kc < 8; ++kc)
                    wf[i][kc] = *(const bf16x8*)(wb +
                        (size_t)(((((wave * 4 + i) * 8) + kc) << 6) + lane) * 8);
            // wait for own-direction Phase A
            if (tid == 0) {
                for (int w = 0; w < 8; ++w)
                    while (ld_rlx(&flags[l * 16 + dir * 8 + w]) == 0) __builtin_amdgcn_s_sleep(2);
                (void)__hip_atomic_load(&flags[l * 16 + dir * 8], __ATOMIC_ACQUIRE, SCOPE_AGENT);
            }
            if (tid < 256) ((unsigned int*)hbuf)[tid] = 0;
            float cst[4] = {0.f, 0.f, 0.f, 0.f};
            __syncthreads();

            unsigned short* zl = zbuf + (size_t)(l & 1) * 32768;
            for (int s = 0; s < 64; ++s) {
                const int t = dir ? (63 - s) : s;
                const int cur = s & 1, nxt = cur ^ 1;
                // prefetch this step's gate biases (Gx) — consumed after MFMAs
                g4u gx[4];
                #pragma unroll
                for (int i = 0; i < 4; ++i) {
                    const int cell = (wave * 4 + i) * 4 + quad;
                    gx[i].q = *(const unsigned long long*)(Gx_d + (size_t)t * 1024 + cell * 4);
                }
                f32x4 acc[4];
                #pragma unroll
                for (int i = 0; i < 4; ++i) acc[i] = (f32x4){0.f, 0.f, 0.f, 0.f};
                #pragma unroll
                for (int kc = 0; kc < 8; ++kc) {
                    bf16x8 b = *(const bf16x8*)&hbuf[cur][kc * 32 + quad * 8];
                    #pragma unroll
                    for (int i = 0; i < 4; ++i) acc[i] = mfma16(wf[i][kc], b, acc[i]);
                }
                if (ln == 0) {
                    #pragma unroll
                    for (int i = 0; i < 4; ++i) {
                        const int cell = (wave * 4 + i) * 4 + quad;
                        float gi = acc[i][0] + (float)gx[i].h[0];
                        float gf = acc[i][1] + (float)gx[i].h[1];
                        float gg = acc[i][2] + (float)gx[i].h[2];
                        float go = acc[i][3] + (float)gx[i].h[3];
                        cst[i] = sigm(gf) * cst[i] + sigm(gi) * tanh_(gg);
                        float h = sigm(go) * tanh_(cst[i]);
                        unsigned short hb16 = __builtin_bit_cast(unsigned short, (__bf16)h);
                        hbuf[nxt][cell] = hb16;
                        zl[(size_t)t * 512 + dir * 256 + cell] = hb16;
                    }
                }
                __syncthreads();
            }
            if (tid == 0) {
                __threadfence();
                __hip_atomic_store(&flags[128 + l * 2 + dir], 1u, __ATOMIC_RELEASE, SCOPE_AGENT);
            }
        }
    }
}

// ---------------------------------------------------------------------------
// fc: zb[64,512]bf16 @ Wb[2560,512]bf16 -> x4b [20][64][128] bf16. Grid = 40.
// ---------------------------------------------------------------------------
__global__ __launch_bounds__(256) void fc_kernel(
    const __bf16* __restrict__ zb, const __bf16* __restrict__ W,
    const float* __restrict__ bb, __bf16* __restrict__ out)
{
    const int tid = threadIdx.x;
    const int wave = tid >> 6, lane = tid & 63, ln = lane & 15, quad = lane >> 4;
    const int nbase = blockIdx.x * 64;
    f32x4 acc[4];
    #pragma unroll
    for (int nt = 0; nt < 4; nt++) acc[nt] = (f32x4){0.f, 0.f, 0.f, 0.f};
    #pragma unroll 2
    for (int kc = 0; kc < 16; kc++) {
        const int k0 = kc * 32 + quad * 8;
        bf16x8 a = *(const bf16x8*)(zb + (size_t)(wave * 16 + ln) * 512 + k0);
        #pragma unroll
        for (int nt = 0; nt < 4; nt++) {
            bf16x8 b = *(const bf16x8*)(W + (size_t)(nbase + nt * 16 + ln) * 512 + k0);
            acc[nt] = mfma16(a, b, acc[nt]);
        }
    }
    #pragma unroll
    for (int nt = 0; nt < 4; nt++) {
        const int n = nbase + nt * 16 + ln;
        const float bv = bb[n];
        #pragma unroll
        for (int reg = 0; reg < 4; reg++) {
            const int t = wave * 16 + quad * 4 + reg;
            out[(size_t)((n >> 7) * 64 + t) * 128 + (n & 127)] = (__bf16)(acc[nt][reg] + bv);
        }
    }
}

// ---------------------------------------------------------------------------
// pool: out[r][t][:] = sum_{s=0..2} vals[3r+s] * in[cols[3r+s]][t][:]
// ---------------------------------------------------------------------------
template <int C>
__global__ __launch_bounds__(256) void pool_kernel(
    const __bf16* __restrict__ in, __bf16* __restrict__ out,
    const int* __restrict__ cols, const float* __restrict__ vals, int V)
{
    const int P = 64 * C / 8;
    const int gid = blockIdx.x * 256 + threadIdx.x;
    if (gid >= V * P) return;
    const int r = gid / P;
    const int rem = gid - r * P;
    float acc[8] = {0.f, 0.f, 0.f, 0.f, 0.f, 0.f, 0.f, 0.f};
    #pragma unroll
    for (int s = 0; s < 3; s++) {
        const int col = cols[3 * r + s];
        const float vv = vals[3 * r + s];
        bf16x8 x = *(const bf16x8*)(in + (size_t)col * 64 * C + rem * 8);
        #pragma unroll
        for (int e = 0; e < 8; e++) acc[e] += vv * (float)x[e];
    }
    bf16x8 ov;
    #pragma unroll
    for (int e = 0; e < 8; e++) ov[e] = (__bf16)acc[e];
    *(bf16x8*)(out + (size_t)r * 64 * C + rem * 8) = ov;
}

// ---------------------------------------------------------------------------
// spiral conv + ELU: one vertex per block. in [Vin][64][CIN] bf16,
// W [COUT][9*CIN] bf16, out [V][64][COUT] bf16.
// ---------------------------------------------------------------------------
template <int CIN, int COUT>
__global__ __launch_bounds__(256) void conv_kernel(
    const __bf16* __restrict__ in, __bf16* __restrict__ out,
    const int* __restrict__ idx, const __bf16* __restrict__ W,
    const float* __restrict__ bias)
{
    constexpr int K = 9 * CIN;
    constexpr int NT = COUT / 16;
    constexpr int NKC = K / 32;
    const int v = blockIdx.x;
    const int tid = threadIdx.x;
    const int wave = tid >> 6, lane = tid & 63, ln = lane & 15, quad = lane >> 4;
    __shared__ int sIdx[9];
    if (tid < 9) sIdx[tid] = idx[v * 9 + tid];
    __syncthreads();
    f32x4 acc[NT];
    #pragma unroll
    for (int nt = 0; nt < NT; nt++) acc[nt] = (f32x4){0.f, 0.f, 0.f, 0.f};
    const int tt = wave * 16 + ln;
    for (int kc = 0; kc < NKC; kc++) {
        const int k0 = kc * 32;
        const int l = k0 / CIN;
        const int c = (k0 & (CIN - 1)) + quad * 8;
        const int row = sIdx[l];
        bf16x8 a = *(const bf16x8*)(in + ((size_t)row * 64 + tt) * CIN + c);
        #pragma unroll
        for (int nt = 0; nt < NT; nt++) {
            bf16x8 b = *(const bf16x8*)(W + (size_t)(nt * 16 + ln) * K + k0 + quad * 8);
            acc[nt] = mfma16(a, b, acc[nt]);
        }
    }
    #pragma unroll
    for (int nt = 0; nt < NT; nt++) {
        const int n = nt * 16 + ln;
        const float bv = bias[n];
        #pragma unroll
        for (int reg = 0; reg < 4; reg++) {
            const int t = wave * 16 + quad * 4 + reg;
            float val = acc[nt][reg] + bv;
            val = val > 0.f ? val : (__expf(val) - 1.f);   // ELU
            out[((size_t)v * 64 + t) * COUT + n] = (__bf16)val;
        }
    }
}

// ---------------------------------------------------------------------------
// head: spiral conv to 3 ch + actor offset -> [64][5023][3] f32
// ---------------------------------------------------------------------------
__global__ __launch_bounds__(256) void head_kernel(
    const __bf16* __restrict__ in, float* __restrict__ out,
    const int* __restrict__ idx, const __bf16* __restrict__ W,
    const float* __restrict__ bias, const float* __restrict__ actor)
{
    const int v = blockIdx.x;
    const int tid = threadIdx.x;
    const int wave = tid >> 6, lane = tid & 63, ln = lane & 15, quad = lane >> 4;
    __shared__ int sIdx[9];
    if (tid < 9) sIdx[tid] = idx[v * 9 + tid];
    __syncthreads();
    f32x4 acc = (f32x4){0.f, 0.f, 0.f, 0.f};
    const int tt = wave * 16 + ln;
    const int rown = ln < 3 ? ln : 0;
    #pragma unroll
    for (int kc = 0; kc < 9; kc++) {
        const int row = sIdx[kc];
        bf16x8 a = *(const bf16x8*)(in + ((size_t)row * 64 + tt) * 32 + quad * 8);
        bf16x8 b = *(const bf16x8*)(W + (size_t)rown * 288 + kc * 32 + quad * 8);
        acc = mfma16(a, b, acc);
    }
    if (ln < 3) {
        const float bv = bias[ln];
        const float av = actor[v * 3 + ln];
        #pragma unroll
        for (int reg = 0; reg < 4; reg++) {
            const int t = wave * 16 + quad * 4 + reg;
            out[((size_t)t * 5023 + v) * 3 + ln] = acc[reg] + bv + av;
        }
    }
}

extern "C" void kernel_launch(void* const* d_in, const int* in_sizes, int n_in,
                              void* d_out, int out_size, void* d_ws, size_t ws_size,
                              hipStream_t stream) {
    const float* audio = (const float*)d_in[0];
    const float* actor = (const float*)d_in[1];
    const float* Wih0  = (const float*)d_in[2];
    const float* Whh0  = (const float*)d_in[3];
    const float* b0    = (const float*)d_in[4];
    const float* WihL  = (const float*)d_in[5];
    const float* WhhL  = (const float*)d_in[6];
    const float* bLs   = (const float*)d_in[7];
    const float* fcW   = (const float*)d_in[8];
    const float* fcb   = (const float*)d_in[9];
    const float* c3W = (const float*)d_in[10]; const float* c3b = (const float*)d_in[11];
    const float* c2W = (const float*)d_in[12]; const float* c2b = (const float*)d_in[13];
    const float* c1W = (const float*)d_in[14]; const float* c1b = (const float*)d_in[15];
    const float* c0W = (const float*)d_in[16]; const float* c0b = (const float*)d_in[17];
    const float* hW  = (const float*)d_in[18]; const float* hb  = (const float*)d_in[19];
    const int* idx0 = (const int*)d_in[20];
    const int* idx1 = (const int*)d_in[21];
    const int* idx2 = (const int*)d_in[22];
    const int* idx3 = (const int*)d_in[23];
    const int* cols0 = (const int*)d_in[25]; const float* vals0 = (const float*)d_in[26];
    const int* cols1 = (const int*)d_in[28]; const float* vals1 = (const float*)d_in[29];
    const int* cols2 = (const int*)d_in[31]; const float* vals2 = (const float*)d_in[32];
    const int* cols3 = (const int*)d_in[34]; const float* vals3 = (const float*)d_in[35];

    char* ws = (char*)d_ws;
    unsigned int*   flags = (unsigned int*)ws;
    unsigned short* zbuf  = (unsigned short*)(ws + ZBUF_OFF);
    unsigned short* GxG   = (unsigned short*)(ws + GX_OFF);
    __bf16*         convWb = (__bf16*)(ws + CONVW_OFF);
    char* arenaA = ws + ARENA_A;
    char* arenaB = ws + ARENA_B;

    __bf16* lw   = (__bf16*)arenaB;                 // lstm bf16 weights (dead after lstm)
    __bf16* fcWb = (__bf16*)(arenaB + 2097152);     // dead after fc (clear of p3)

    __bf16* x4b = (__bf16*)arenaA;   // [20][64][128]
    __bf16* p3  = (__bf16*)arenaB;   // [79][64][128]
    __bf16* c3o = (__bf16*)arenaA;   // [79][64][128]
    __bf16* p2  = (__bf16*)arenaB;   // [314][64][128]
    __bf16* c2o = (__bf16*)arenaA;   // [314][64][64]
    __bf16* p1  = (__bf16*)arenaB;   // [1256][64][64]
    __bf16* c1o = (__bf16*)arenaA;   // [1256][64][64]
    __bf16* p0  = (__bf16*)arenaB;   // [5023][64][64]
    __bf16* c0o = (__bf16*)arenaA;   // [5023][64][32]

    hipMemsetAsync(ws, 0, 1024, stream);   // flags

    precvt_lstm<<<5632, 256, 0, stream>>>(Wih0, WihL, lw);
    precvt_whh<<<1280, 256, 0, stream>>>(Whh0, WhhL, lw + O_WHHP);
    lstm_fused<<<18, 1024, 0, stream>>>(audio, lw, lw + O_WHHP, b0, bLs,
                                        GxG, flags, zbuf);
    precvt_dec<<<1552, 256, 0, stream>>>(fcW, c3W, c2W, c1W, c0W, hW, fcWb, convWb);

    fc_kernel<<<40, 256, 0, stream>>>((const __bf16*)zbuf, fcWb, fcb, x4b);

    { int n = 79 * 64 * 128 / 8;
      pool_kernel<128><<<(n + 255) / 256, 256, 0, stream>>>(x4b, p3, cols3, vals3, 79);
      conv_kernel<128, 128><<<79, 256, 0, stream>>>(p3, c3o, idx3, convWb + 0, c3b); }
    { int n = 314 * 64 * 128 / 8;
      pool_kernel<128><<<(n + 255) / 256, 256, 0, stream>>>(c3o, p2, cols2, vals2, 314);
      conv_kernel<128, 64><<<314, 256, 0, stream>>>(p2, c2o, idx2, convWb + 147456, c2b); }
    { int n = 1256 * 64 * 64 / 8;
      pool_kernel<64><<<(n + 255) / 256, 256, 0, stream>>>(c2o, p1, cols1, vals1, 1256);
      conv_kernel<64, 64><<<1256, 256, 0, stream>>>(p1, c1o, idx1, convWb + 221184, c1b); }
    { int n = 5023 * 64 * 64 / 8;
      pool_kernel<64><<<(n + 255) / 256, 256, 0, stream>>>(c1o, p0, cols0, vals0, 5023);
      conv_kernel<64, 32><<<5023, 256, 0, stream>>>(p0, c0o, idx0, convWb + 258048, c0b); }

    head_kernel<<<5023, 256, 0, stream>>>(c0o, (float*)d_out, idx0, convWb + 276480, hb, actor);
}

// Round 5
// 1225.465 us; speedup vs baseline: 2.6906x; 2.6906x over previous
//
#include <hip/hip_runtime.h>
#include <hip/hip_bf16.h>

typedef __attribute__((ext_vector_type(8))) __bf16 bf16x8;
typedef __attribute__((ext_vector_type(4))) float  f32x4;
typedef __attribute__((ext_vector_type(4))) int    i32x4;

#define SCOPE_AGENT __HIP_MEMORY_SCOPE_AGENT

static __device__ __forceinline__ f32x4 mfma16(bf16x8 a, bf16x8 b, f32x4 c) {
    return __builtin_amdgcn_mfma_f32_16x16x32_bf16(a, b, c, 0, 0, 0);
}
static __device__ __forceinline__ i32x4 mfma_i8(i32x4 a, i32x4 b, i32x4 c) {
    return __builtin_amdgcn_mfma_i32_16x16x64_i8(a, b, c, 0, 0, 0);
}
static __device__ __forceinline__ float sigm(float x)  { return 1.0f / (1.0f + __expf(-x)); }
static __device__ __forceinline__ float tanh_(float x) { return 1.0f - 2.0f / (__expf(2.0f * x) + 1.0f); }

static __device__ __forceinline__ bf16x8 cvt8(const float* __restrict__ p) {
    const float4* q = (const float4*)p;
    float4 a = q[0], b = q[1];
    bf16x8 r;
    r[0] = (__bf16)a.x; r[1] = (__bf16)a.y; r[2] = (__bf16)a.z; r[3] = (__bf16)a.w;
    r[4] = (__bf16)b.x; r[5] = (__bf16)b.y; r[6] = (__bf16)b.z; r[7] = (__bf16)b.w;
    return r;
}
static __device__ __forceinline__ unsigned int ld_rlx(const unsigned int* p) {
    return __hip_atomic_load((unsigned int*)p, __ATOMIC_RELAXED, SCOPE_AGENT);
}
union g4u { unsigned long long q; __bf16 h[4]; };

// ---------------------------------------------------------------------------
// ws layout (bytes):
//   0        flags (1024, zeroed): pa_done[l*16+bid]; z_done @ u32[128+l*2+dir]
//   1024     zbuf  [2][64][512] bf16 = 131072   (zbuf0 survives -> fc)
//   132096   Gx_g  [2][64][1024] bf16 = 262144  (dead after lstm)
//   66560    convWb overlay (554688) over zbuf1+Gx, written after lstm
//   621248   arenaA (20,574,208)
//   21195456 arenaB (41,148,416):
//              Wih bf16 @ +0 (11,534,336 B, dead after lstm)
//              WhhQ i8  @ +11,534,336 (2,621,440 B, dead after lstm)
//              swp f32  @ +14,155,776 (40,960 B, dead after lstm)
//              fcWb     @ +2,097,152 (written after lstm, dead after fc)
// ---------------------------------------------------------------------------
#define ZBUF_OFF   1024
#define GX_OFF     132096
#define CONVW_OFF  66560
#define ARENA_A    621248
#define ARENA_B    21195456
#define WHHQ_BOFF  11534336
#define SWP_BOFF   14155776
// Wih bf16 element offsets in arenaB
#define O_WIH0  0            // [2][1024][768]
#define O_WIHL  1572864      // [4][2][1024][512]

// ---------------------------------------------------------------------------
// one-time f32->bf16: Wih plain copy
// ---------------------------------------------------------------------------
__global__ __launch_bounds__(256) void precvt_lstm(
    const float* __restrict__ Wih0, const float* __restrict__ WihL,
    __bf16* __restrict__ out)
{
    int f = (blockIdx.x * 256 + threadIdx.x) * 4;
    const float* src; int off;
    if (f < 1572864) { src = Wih0; off = f; }
    else             { src = WihL; off = f - 1572864; }
    float4 v = *(const float4*)(src + off);
    g4u u;
    u.h[0] = (__bf16)v.x; u.h[1] = (__bf16)v.y; u.h[2] = (__bf16)v.z; u.h[3] = (__bf16)v.w;
    *(unsigned long long*)(out + f) = u.q;
}

// ---------------------------------------------------------------------------
// one-time: Whh -> per-row-absmax int8 in A-fragment order + scales.
// One wave per (dl, row r). r = gate*256 + cell; m = cell*4 + gate.
// Fragment addressing (byte): (((dl*64 + mt)*4 + kc)*64 + (quad*16+ln))*16 + j
//   mt=m>>4, ln=m&15, kc=k>>6, quad=(k>>4)&3, j=k&15.
// swp[dl*1024 + cell*4 + gate] = absmax/127.
// ---------------------------------------------------------------------------
__global__ __launch_bounds__(64) void precvt_whhq(
    const float* __restrict__ Whh0, const float* __restrict__ WhhL,
    signed char* __restrict__ WhhQ, float* __restrict__ swp)
{
    const int g  = blockIdx.x;          // 0..10239
    const int dl = g >> 10;
    const int r  = g & 1023;
    const int lane = threadIdx.x;
    const float* src = (dl < 2 ? Whh0 + (size_t)dl * 262144
                               : WhhL + (size_t)(dl - 2) * 262144) + (size_t)r * 256;
    float4 v = *(const float4*)(src + lane * 4);
    float am = fmaxf(fmaxf(fabsf(v.x), fabsf(v.y)), fmaxf(fabsf(v.z), fabsf(v.w)));
    #pragma unroll
    for (int m = 1; m < 64; m <<= 1) am = fmaxf(am, __shfl_xor(am, m));
    const float inv = am > 0.f ? 127.f / am : 0.f;
    int q0 = __float2int_rn(v.x * inv), q1 = __float2int_rn(v.y * inv);
    int q2 = __float2int_rn(v.z * inv), q3 = __float2int_rn(v.w * inv);
    unsigned pk = (q0 & 255) | ((q1 & 255) << 8) | ((q2 & 255) << 16) | ((q3 & 255) << 24);
    const int gate = r >> 8, cell = r & 255;
    const int m  = cell * 4 + gate;
    const int ln = m & 15, mt = m >> 4;
    const int k  = lane * 4;
    const int kc = k >> 6, quad = (k >> 4) & 3, j = k & 15;
    size_t addr = ((((size_t)dl * 64 + mt) * 4 + kc) * 64 + (quad * 16 + ln)) * 16 + j;
    *(unsigned*)(WhhQ + addr) = pk;
    if (lane == 0) swp[(size_t)dl * 1024 + cell * 4 + gate] = am / 127.f;
}

// decoder weights f32->bf16 (after lstm; convWb overlays dead lstm buffers)
__global__ __launch_bounds__(256) void precvt_dec(
    const float* __restrict__ fcW, const float* __restrict__ c3W,
    const float* __restrict__ c2W, const float* __restrict__ c1W,
    const float* __restrict__ c0W, const float* __restrict__ hW,
    __bf16* __restrict__ fcWb, __bf16* __restrict__ convWb)
{
    int f = (blockIdx.x * 256 + threadIdx.x) * 4;
    if (f >= 1588064) return;
    const float* src; int off; __bf16* dst; int doff;
    if (f < 1310720) { src = fcW; off = f; dst = fcWb; doff = f; }
    else {
        int g = f - 1310720; dst = convWb; doff = g;
        if (g < 147456)      { src = c3W; off = g; }
        else if (g < 221184) { src = c2W; off = g - 147456; }
        else if (g < 258048) { src = c1W; off = g - 221184; }
        else if (g < 276480) { src = c0W; off = g - 258048; }
        else                 { src = hW;  off = g - 276480; }
    }
    float4 v = *(const float4*)(src + off);
    g4u u;
    u.h[0] = (__bf16)v.x; u.h[1] = (__bf16)v.y; u.h[2] = (__bf16)v.z; u.h[3] = (__bf16)v.w;
    *(unsigned long long*)(dst + doff) = u.q;
}

// ---------------------------------------------------------------------------
// Fused LSTM, grid = 18 x 1024:
//  bid 0..15 : Phase-A WGs (Gx = Wih@x + b per layer, bf16 MFMA)
//  bid 16,17 : recurrence WGs, one per direction, one CU each:
//    Whh int8 register-resident (wf[4][4] i32x4 = 64 VGPRs), h int8 in LDS
//    ping-pong, i8 MFMA K=64 (exact i32 accumulate), per-row scales.
//    Lanes ln<4 each own ONE cell (acc replicated across ln).
// m = cell*4 + gate everywhere; weight row r = gate*256 + cell.
// ---------------------------------------------------------------------------
__global__ __launch_bounds__(1024) __attribute__((amdgpu_waves_per_eu(4, 4)))
void lstm_fused(
    const float* __restrict__ audio,
    const __bf16* __restrict__ WihB,
    const signed char* __restrict__ WhhQ,
    const float* __restrict__ swp,
    const float* __restrict__ b0, const float* __restrict__ bL,
    unsigned short* __restrict__ Gx_g,  // [2][64][1024] bf16 bits
    unsigned int* __restrict__ flags,
    unsigned short* __restrict__ zbuf)  // [2][64][512] bf16 bits
{
    const int bid = blockIdx.x;
    const int tid = threadIdx.x;
    const int wave = tid >> 6, lane = tid & 63, ln = lane & 15, quad = lane >> 4;

    if (bid < 16) {
        // ---------------- Phase A ----------------
        const int dir = bid >> 3, sub = bid & 7;
        const int mt = wave >> 1, ntb = (wave & 1) * 2;
        for (int l = 0; l < 5; ++l) {
            if (l > 0) {
                if (tid == 0) {
                    while (ld_rlx(&flags[128 + (l - 1) * 2 + 0]) == 0) __builtin_amdgcn_s_sleep(16);
                    while (ld_rlx(&flags[128 + (l - 1) * 2 + 1]) == 0) __builtin_amdgcn_s_sleep(16);
                    (void)__hip_atomic_load(&flags[128 + (l - 1) * 2], __ATOMIC_ACQUIRE, SCOPE_AGENT);
                }
                __syncthreads();
            }
            const int Din = l ? 512 : 768;
            const __bf16* Wih_l = l ? (WihB + O_WIHL + (size_t)((l - 1) * 2 + dir) * 524288)
                                    : (WihB + (size_t)dir * 786432);
            const float* b_l = l ? (bL + (size_t)((l - 1) * 2 + dir) * 1024)
                                 : (b0 + (size_t)dir * 1024);
            const __bf16* zp = (const __bf16*)(zbuf + (size_t)((l - 1) & 1) * 32768);

            f32x4 acc[2];
            acc[0] = (f32x4){0.f, 0.f, 0.f, 0.f};
            acc[1] = (f32x4){0.f, 0.f, 0.f, 0.f};
            const int m_a = sub * 128 + mt * 16 + ln;
            const int r_a = (m_a & 3) * 256 + (m_a >> 2);
            const int Kc = Din >> 5;
            for (int kc = 0; kc < Kc; ++kc) {
                const int k0 = kc * 32 + quad * 8;
                bf16x8 afr = *(const bf16x8*)(Wih_l + (size_t)r_a * Din + k0);
                #pragma unroll
                for (int e = 0; e < 2; ++e) {
                    const int t = (ntb + e) * 16 + ln;
                    bf16x8 bfr = l ? *(const bf16x8*)(zp + (size_t)t * 512 + k0)
                                   : cvt8(audio + (size_t)t * 768 + k0);
                    acc[e] = mfma16(afr, bfr, acc[e]);
                }
            }
            #pragma unroll
            for (int reg = 0; reg < 4; ++reg) {
                const int m_row = sub * 128 + mt * 16 + quad * 4 + reg;
                const int r_row = (m_row & 3) * 256 + (m_row >> 2);
                const float bv = b_l[r_row];
                #pragma unroll
                for (int e = 0; e < 2; ++e) {
                    const int t = (ntb + e) * 16 + ln;
                    __bf16 v = (__bf16)(acc[e][reg] + bv);
                    Gx_g[(size_t)dir * 65536 + t * 1024 + m_row] =
                        __builtin_bit_cast(unsigned short, v);
                }
            }
            __syncthreads();
            if (tid == 0) {
                __threadfence();
                __hip_atomic_store(&flags[l * 16 + bid], 1u, __ATOMIC_RELEASE, SCOPE_AGENT);
            }
        }
    } else {
        // ---------------- recurrence ----------------
        const int dir = bid - 16;
        const unsigned short* Gx_d = Gx_g + (size_t)dir * 65536;
        __shared__ __align__(16) signed char hq[2][256];
        const int mycell = (wave * 4 + ln) * 4 + quad;   // valid when ln < 4

        for (int l = 0; l < 5; ++l) {
            const int dl = l * 2 + dir;
            // weights first (overlaps Phase-A wait)
            i32x4 wf[4][4];
            const i32x4* wb = (const i32x4*)(WhhQ + (size_t)dl * 262144);
            #pragma unroll
            for (int i = 0; i < 4; ++i)
                #pragma unroll
                for (int kc = 0; kc < 4; ++kc)
                    wf[i][kc] = wb[(size_t)(((wave * 4 + i) * 4 + kc)) * 64 + lane];
            float sc0 = 0.f, sc1 = 0.f, sc2 = 0.f, sc3 = 0.f;
            if (ln < 4) {
                float4 s4 = *(const float4*)(swp + (size_t)dl * 1024 + mycell * 4);
                const float f = 1.f / 127.f;
                sc0 = s4.x * f; sc1 = s4.y * f; sc2 = s4.z * f; sc3 = s4.w * f;
            }
            if (tid == 0) {
                for (int w = 0; w < 8; ++w)
                    while (ld_rlx(&flags[l * 16 + dir * 8 + w]) == 0) __builtin_amdgcn_s_sleep(16);
                (void)__hip_atomic_load(&flags[l * 16 + dir * 8], __ATOMIC_ACQUIRE, SCOPE_AGENT);
            }
            if (tid < 64) ((unsigned int*)hq[0])[tid] = 0;
            float cst = 0.f;
            __syncthreads();

            unsigned short* zl = zbuf + (size_t)(l & 1) * 32768;
            for (int s = 0; s < 64; ++s) {
                const int t = dir ? (63 - s) : s;
                const int cur = s & 1, nxt = cur ^ 1;
                g4u gx; gx.q = 0;
                if (ln < 4) gx.q = *(const unsigned long long*)(Gx_d + (size_t)t * 1024 + mycell * 4);
                i32x4 acc[4];
                #pragma unroll
                for (int i = 0; i < 4; ++i) acc[i] = (i32x4){0, 0, 0, 0};
                #pragma unroll
                for (int kc = 0; kc < 4; ++kc) {
                    i32x4 b = *(const i32x4*)&hq[cur][kc * 64 + quad * 16];
                    #pragma unroll
                    for (int i = 0; i < 4; ++i) acc[i] = mfma_i8(wf[i][kc], b, acc[i]);
                }
                if (ln < 4) {
                    i32x4 a = acc[0];
                    if (ln == 1) a = acc[1];
                    if (ln == 2) a = acc[2];
                    if (ln == 3) a = acc[3];
                    float gi = (float)a[0] * sc0 + (float)gx.h[0];
                    float gf = (float)a[1] * sc1 + (float)gx.h[1];
                    float gg = (float)a[2] * sc2 + (float)gx.h[2];
                    float go = (float)a[3] * sc3 + (float)gx.h[3];
                    cst = sigm(gf) * cst + sigm(gi) * tanh_(gg);
                    float h = sigm(go) * tanh_(cst);
                    hq[nxt][mycell] = (signed char)__float2int_rn(h * 127.f);
                    zl[(size_t)t * 512 + dir * 256 + mycell] =
                        __builtin_bit_cast(unsigned short, (__bf16)h);
                }
                __syncthreads();
            }
            if (tid == 0) {
                __threadfence();
                __hip_atomic_store(&flags[128 + l * 2 + dir], 1u, __ATOMIC_RELEASE, SCOPE_AGENT);
            }
        }
    }
}

// ---------------------------------------------------------------------------
// fc: zb[64,512]bf16 @ Wb[2560,512]bf16 -> x4b [20][64][128] bf16. Grid = 40.
// ---------------------------------------------------------------------------
__global__ __launch_bounds__(256) void fc_kernel(
    const __bf16* __restrict__ zb, const __bf16* __restrict__ W,
    const float* __restrict__ bb, __bf16* __restrict__ out)
{
    const int tid = threadIdx.x;
    const int wave = tid >> 6, lane = tid & 63, ln = lane & 15, quad = lane >> 4;
    const int nbase = blockIdx.x * 64;
    f32x4 acc[4];
    #pragma unroll
    for (int nt = 0; nt < 4; nt++) acc[nt] = (f32x4){0.f, 0.f, 0.f, 0.f};
    #pragma unroll 2
    for (int kc = 0; kc < 16; kc++) {
        const int k0 = kc * 32 + quad * 8;
        bf16x8 a = *(const bf16x8*)(zb + (size_t)(wave * 16 + ln) * 512 + k0);
        #pragma unroll
        for (int nt = 0; nt < 4; nt++) {
            bf16x8 b = *(const bf16x8*)(W + (size_t)(nbase + nt * 16 + ln) * 512 + k0);
            acc[nt] = mfma16(a, b, acc[nt]);
        }
    }
    #pragma unroll
    for (int nt = 0; nt < 4; nt++) {
        const int n = nbase + nt * 16 + ln;
        const float bv = bb[n];
        #pragma unroll
        for (int reg = 0; reg < 4; reg++) {
            const int t = wave * 16 + quad * 4 + reg;
            out[(size_t)((n >> 7) * 64 + t) * 128 + (n & 127)] = (__bf16)(acc[nt][reg] + bv);
        }
    }
}

// ---------------------------------------------------------------------------
// pool: out[r][t][:] = sum_{s=0..2} vals[3r+s] * in[cols[3r+s]][t][:]
// ---------------------------------------------------------------------------
template <int C>
__global__ __launch_bounds__(256) void pool_kernel(
    const __bf16* __restrict__ in, __bf16* __restrict__ out,
    const int* __restrict__ cols, const float* __restrict__ vals, int V)
{
    const int P = 64 * C / 8;
    const int gid = blockIdx.x * 256 + threadIdx.x;
    if (gid >= V * P) return;
    const int r = gid / P;
    const int rem = gid - r * P;
    float acc[8] = {0.f, 0.f, 0.f, 0.f, 0.f, 0.f, 0.f, 0.f};
    #pragma unroll
    for (int s = 0; s < 3; s++) {
        const int col = cols[3 * r + s];
        const float vv = vals[3 * r + s];
        bf16x8 x = *(const bf16x8*)(in + (size_t)col * 64 * C + rem * 8);
        #pragma unroll
        for (int e = 0; e < 8; e++) acc[e] += vv * (float)x[e];
    }
    bf16x8 ov;
    #pragma unroll
    for (int e = 0; e < 8; e++) ov[e] = (__bf16)acc[e];
    *(bf16x8*)(out + (size_t)r * 64 * C + rem * 8) = ov;
}

// ---------------------------------------------------------------------------
// spiral conv + ELU: one vertex per block. in [Vin][64][CIN] bf16,
// W [COUT][9*CIN] bf16, out [V][64][COUT] bf16.
// ---------------------------------------------------------------------------
template <int CIN, int COUT>
__global__ __launch_bounds__(256) void conv_kernel(
    const __bf16* __restrict__ in, __bf16* __restrict__ out,
    const int* __restrict__ idx, const __bf16* __restrict__ W,
    const float* __restrict__ bias)
{
    constexpr int K = 9 * CIN;
    constexpr int NT = COUT / 16;
    constexpr int NKC = K / 32;
    const int v = blockIdx.x;
    const int tid = threadIdx.x;
    const int wave = tid >> 6, lane = tid & 63, ln = lane & 15, quad = lane >> 4;
    __shared__ int sIdx[9];
    if (tid < 9) sIdx[tid] = idx[v * 9 + tid];
    __syncthreads();
    f32x4 acc[NT];
    #pragma unroll
    for (int nt = 0; nt < NT; nt++) acc[nt] = (f32x4){0.f, 0.f, 0.f, 0.f};
    const int tt = wave * 16 + ln;
    for (int kc = 0; kc < NKC; kc++) {
        const int k0 = kc * 32;
        const int l = k0 / CIN;
        const int c = (k0 & (CIN - 1)) + quad * 8;
        const int row = sIdx[l];
        bf16x8 a = *(const bf16x8*)(in + ((size_t)row * 64 + tt) * CIN + c);
        #pragma unroll
        for (int nt = 0; nt < NT; nt++) {
            bf16x8 b = *(const bf16x8*)(W + (size_t)(nt * 16 + ln) * K + k0 + quad * 8);
            acc[nt] = mfma16(a, b, acc[nt]);
        }
    }
    #pragma unroll
    for (int nt = 0; nt < NT; nt++) {
        const int n = nt * 16 + ln;
        const float bv = bias[n];
        #pragma unroll
        for (int reg = 0; reg < 4; reg++) {
            const int t = wave * 16 + quad * 4 + reg;
            float val = acc[nt][reg] + bv;
            val = val > 0.f ? val : (__expf(val) - 1.f);   // ELU
            out[((size_t)v * 64 + t) * COUT + n] = (__bf16)val;
        }
    }
}

// ---------------------------------------------------------------------------
// head: spiral conv to 3 ch + actor offset -> [64][5023][3] f32
// ---------------------------------------------------------------------------
__global__ __launch_bounds__(256) void head_kernel(
    const __bf16* __restrict__ in, float* __restrict__ out,
    const int* __restrict__ idx, const __bf16* __restrict__ W,
    const float* __restrict__ bias, const float* __restrict__ actor)
{
    const int v = blockIdx.x;
    const int tid = threadIdx.x;
    const int wave = tid >> 6, lane = tid & 63, ln = lane & 15, quad = lane >> 4;
    __shared__ int sIdx[9];
    if (tid < 9) sIdx[tid] = idx[v * 9 + tid];
    __syncthreads();
    f32x4 acc = (f32x4){0.f, 0.f, 0.f, 0.f};
    const int tt = wave * 16 + ln;
    const int rown = ln < 3 ? ln : 0;
    #pragma unroll
    for (int kc = 0; kc < 9; kc++) {
        const int row = sIdx[kc];
        bf16x8 a = *(const bf16x8*)(in + ((size_t)row * 64 + tt) * 32 + quad * 8);
        bf16x8 b = *(const bf16x8*)(W + (size_t)rown * 288 + kc * 32 + quad * 8);
        acc = mfma16(a, b, acc);
    }
    if (ln < 3) {
        const float bv = bias[ln];
        const float av = actor[v * 3 + ln];
        #pragma unroll
        for (int reg = 0; reg < 4; reg++) {
            const int t = wave * 16 + quad * 4 + reg;
            out[((size_t)t * 5023 + v) * 3 + ln] = acc[reg] + bv + av;
        }
    }
}

extern "C" void kernel_launch(void* const* d_in, const int* in_sizes, int n_in,
                              void* d_out, int out_size, void* d_ws, size_t ws_size,
                              hipStream_t stream) {
    const float* audio = (const float*)d_in[0];
    const float* actor = (const float*)d_in[1];
    const float* Wih0  = (const float*)d_in[2];
    const float* Whh0  = (const float*)d_in[3];
    const float* b0    = (const float*)d_in[4];
    const float* WihL  = (const float*)d_in[5];
    const float* WhhL  = (const float*)d_in[6];
    const float* bLs   = (const float*)d_in[7];
    const float* fcW   = (const float*)d_in[8];
    const float* fcb   = (const float*)d_in[9];
    const float* c3W = (const float*)d_in[10]; const float* c3b = (const float*)d_in[11];
    const float* c2W = (const float*)d_in[12]; const float* c2b = (const float*)d_in[13];
    const float* c1W = (const float*)d_in[14]; const float* c1b = (const float*)d_in[15];
    const float* c0W = (const float*)d_in[16]; const float* c0b = (const float*)d_in[17];
    const float* hW  = (const float*)d_in[18]; const float* hb  = (const float*)d_in[19];
    const int* idx0 = (const int*)d_in[20];
    const int* idx1 = (const int*)d_in[21];
    const int* idx2 = (const int*)d_in[22];
    const int* idx3 = (const int*)d_in[23];
    const int* cols0 = (const int*)d_in[25]; const float* vals0 = (const float*)d_in[26];
    const int* cols1 = (const int*)d_in[28]; const float* vals1 = (const float*)d_in[29];
    const int* cols2 = (const int*)d_in[31]; const float* vals2 = (const float*)d_in[32];
    const int* cols3 = (const int*)d_in[34]; const float* vals3 = (const float*)d_in[35];

    char* ws = (char*)d_ws;
    unsigned int*   flags = (unsigned int*)ws;
    unsigned short* zbuf  = (unsigned short*)(ws + ZBUF_OFF);
    unsigned short* GxG   = (unsigned short*)(ws + GX_OFF);
    __bf16*         convWb = (__bf16*)(ws + CONVW_OFF);
    char* arenaA = ws + ARENA_A;
    char* arenaB = ws + ARENA_B;

    __bf16*      lw   = (__bf16*)arenaB;                      // Wih bf16
    signed char* whhq = (signed char*)(arenaB + WHHQ_BOFF);   // Whh int8
    float*       swp  = (float*)(arenaB + SWP_BOFF);          // row scales
    __bf16*      fcWb = (__bf16*)(arenaB + 2097152);          // dead after fc

    __bf16* x4b = (__bf16*)arenaA;   // [20][64][128]
    __bf16* p3  = (__bf16*)arenaB;   // [79][64][128]
    __bf16* c3o = (__bf16*)arenaA;   // [79][64][128]
    __bf16* p2  = (__bf16*)arenaB;   // [314][64][128]
    __bf16* c2o = (__bf16*)arenaA;   // [314][64][64]
    __bf16* p1  = (__bf16*)arenaB;   // [1256][64][64]
    __bf16* c1o = (__bf16*)arenaA;   // [1256][64][64]
    __bf16* p0  = (__bf16*)arenaB;   // [5023][64][64]
    __bf16* c0o = (__bf16*)arenaA;   // [5023][64][32]

    hipMemsetAsync(ws, 0, 1024, stream);   // flags

    precvt_lstm<<<5632, 256, 0, stream>>>(Wih0, WihL, lw);
    precvt_whhq<<<10240, 64, 0, stream>>>(Whh0, WhhL, whhq, swp);
    lstm_fused<<<18, 1024, 0, stream>>>(audio, lw, whhq, swp, b0, bLs,
                                        GxG, flags, zbuf);
    precvt_dec<<<1552, 256, 0, stream>>>(fcW, c3W, c2W, c1W, c0W, hW, fcWb, convWb);

    fc_kernel<<<40, 256, 0, stream>>>((const __bf16*)zbuf, fcWb, fcb, x4b);

    { int n = 79 * 64 * 128 / 8;
      pool_kernel<128><<<(n + 255) / 256, 256, 0, stream>>>(x4b, p3, cols3, vals3, 79);
      conv_kernel<128, 128><<<79, 256, 0, stream>>>(p3, c3o, idx3, convWb + 0, c3b); }
    { int n = 314 * 64 * 128 / 8;
      pool_kernel<128><<<(n + 255) / 256, 256, 0, stream>>>(c3o, p2, cols2, vals2, 314);
      conv_kernel<128, 64><<<314, 256, 0, stream>>>(p2, c2o, idx2, convWb + 147456, c2b); }
    { int n = 1256 * 64 * 64 / 8;
      pool_kernel<64><<<(n + 255) / 256, 256, 0, stream>>>(c2o, p1, cols1, vals1, 1256);
      conv_kernel<64, 64><<<1256, 256, 0, stream>>>(p1, c1o, idx1, convWb + 221184, c1b); }
    { int n = 5023 * 64 * 64 / 8;
      pool_kernel<64><<<(n + 255) / 256, 256, 0, stream>>>(c1o, p0, cols0, vals0, 5023);
      conv_kernel<64, 32><<<5023, 256, 0, stream>>>(p0, c0o, idx0, convWb + 258048, c0b); }

    head_kernel<<<5023, 256, 0, stream>>>(c0o, (float*)d_out, idx0, convWb + 276480, hb, actor);
}

// Round 6
// 1044.654 us; speedup vs baseline: 3.1562x; 1.1731x over previous
//
#include <hip/hip_runtime.h>
#include <hip/hip_bf16.h>

typedef __attribute__((ext_vector_type(8))) __bf16 bf16x8;
typedef __attribute__((ext_vector_type(4))) float  f32x4;
typedef __attribute__((ext_vector_type(4))) int    i32x4;

#define SCOPE_AGENT __HIP_MEMORY_SCOPE_AGENT

static __device__ __forceinline__ f32x4 mfma16(bf16x8 a, bf16x8 b, f32x4 c) {
    return __builtin_amdgcn_mfma_f32_16x16x32_bf16(a, b, c, 0, 0, 0);
}
static __device__ __forceinline__ i32x4 mfma_i8(i32x4 a, i32x4 b, i32x4 c) {
    return __builtin_amdgcn_mfma_i32_16x16x64_i8(a, b, c, 0, 0, 0);
}
static __device__ __forceinline__ float sigm(float x)  { return 1.0f / (1.0f + __expf(-x)); }
static __device__ __forceinline__ float tanh_(float x) { return 1.0f - 2.0f / (__expf(2.0f * x) + 1.0f); }

static __device__ __forceinline__ bf16x8 cvt8(const float* __restrict__ p) {
    const float4* q = (const float4*)p;
    float4 a = q[0], b = q[1];
    bf16x8 r;
    r[0] = (__bf16)a.x; r[1] = (__bf16)a.y; r[2] = (__bf16)a.z; r[3] = (__bf16)a.w;
    r[4] = (__bf16)b.x; r[5] = (__bf16)b.y; r[6] = (__bf16)b.z; r[7] = (__bf16)b.w;
    return r;
}
static __device__ __forceinline__ unsigned int ld_rlx(const unsigned int* p) {
    return __hip_atomic_load((unsigned int*)p, __ATOMIC_RELAXED, SCOPE_AGENT);
}
union g4u { unsigned long long q; __bf16 h[4]; };

// ---------------------------------------------------------------------------
// ws layout (bytes): identical to round 5.
//   0        flags (1024, zeroed): pa_done[l*16+bid]; z_done @ u32[128+l*2+dir]
//   1024     zbuf  [2][64][512] bf16 = 131072   (zbuf0 survives -> fc)
//   132096   Gx_g  [2][64][1024] bf16 = 262144  (dead after lstm)
//   66560    convWb overlay (554688) over zbuf1+Gx, written after lstm
//   621248   arenaA (20,574,208)
//   21195456 arenaB: Wih bf16 @0; WhhQ i8 @11,534,336; swp @14,155,776;
//            fcWb @2,097,152 (written after lstm, dead after fc)
// ---------------------------------------------------------------------------
#define ZBUF_OFF   1024
#define GX_OFF     132096
#define CONVW_OFF  66560
#define ARENA_A    621248
#define ARENA_B    21195456
#define WHHQ_BOFF  11534336
#define SWP_BOFF   14155776
#define O_WIH0  0            // [2][1024][768]
#define O_WIHL  1572864      // [4][2][1024][512]

// ---------------------------------------------------------------------------
// one-time f32->bf16: Wih plain copy
// ---------------------------------------------------------------------------
__global__ __launch_bounds__(256) void precvt_lstm(
    const float* __restrict__ Wih0, const float* __restrict__ WihL,
    __bf16* __restrict__ out)
{
    int f = (blockIdx.x * 256 + threadIdx.x) * 4;
    const float* src; int off;
    if (f < 1572864) { src = Wih0; off = f; }
    else             { src = WihL; off = f - 1572864; }
    float4 v = *(const float4*)(src + off);
    g4u u;
    u.h[0] = (__bf16)v.x; u.h[1] = (__bf16)v.y; u.h[2] = (__bf16)v.z; u.h[3] = (__bf16)v.w;
    *(unsigned long long*)(out + f) = u.q;
}

// ---------------------------------------------------------------------------
// one-time: Whh -> per-row-absmax int8 in A-fragment order + scales.
// One wave per (dl, row r). r = gate*256 + cell; m = cell*4 + gate.
// Fragment byte addr: (((dl*64 + mt)*4 + kc)*64 + lane)*16 + j,
//   mt=m>>4 (lane&15 = m&15), kc=k>>6, lane>>4=(k>>4)&3, j=k&15.
// swp[dl*1024 + cell*4 + gate] = absmax/127.
// ---------------------------------------------------------------------------
__global__ __launch_bounds__(64) void precvt_whhq(
    const float* __restrict__ Whh0, const float* __restrict__ WhhL,
    signed char* __restrict__ WhhQ, float* __restrict__ swp)
{
    const int g  = blockIdx.x;          // 0..10239
    const int dl = g >> 10;
    const int r  = g & 1023;
    const int lane = threadIdx.x;
    const float* src = (dl < 2 ? Whh0 + (size_t)dl * 262144
                               : WhhL + (size_t)(dl - 2) * 262144) + (size_t)r * 256;
    float4 v = *(const float4*)(src + lane * 4);
    float am = fmaxf(fmaxf(fabsf(v.x), fabsf(v.y)), fmaxf(fabsf(v.z), fabsf(v.w)));
    #pragma unroll
    for (int m = 1; m < 64; m <<= 1) am = fmaxf(am, __shfl_xor(am, m));
    const float inv = am > 0.f ? 127.f / am : 0.f;
    int q0 = __float2int_rn(v.x * inv), q1 = __float2int_rn(v.y * inv);
    int q2 = __float2int_rn(v.z * inv), q3 = __float2int_rn(v.w * inv);
    unsigned pk = (q0 & 255) | ((q1 & 255) << 8) | ((q2 & 255) << 16) | ((q3 & 255) << 24);
    const int gate = r >> 8, cell = r & 255;
    const int m  = cell * 4 + gate;
    const int ln = m & 15, mt = m >> 4;
    const int k  = lane * 4;
    const int kc = k >> 6, quad = (k >> 4) & 3, j = k & 15;
    size_t addr = ((((size_t)dl * 64 + mt) * 4 + kc) * 64 + (quad * 16 + ln)) * 16 + j;
    *(unsigned*)(WhhQ + addr) = pk;
    if (lane == 0) swp[(size_t)dl * 1024 + cell * 4 + gate] = am / 127.f;
}

// decoder weights f32->bf16
__global__ __launch_bounds__(256) void precvt_dec(
    const float* __restrict__ fcW, const float* __restrict__ c3W,
    const float* __restrict__ c2W, const float* __restrict__ c1W,
    const float* __restrict__ c0W, const float* __restrict__ hW,
    __bf16* __restrict__ fcWb, __bf16* __restrict__ convWb)
{
    int f = (blockIdx.x * 256 + threadIdx.x) * 4;
    if (f >= 1588064) return;
    const float* src; int off; __bf16* dst; int doff;
    if (f < 1310720) { src = fcW; off = f; dst = fcWb; doff = f; }
    else {
        int g = f - 1310720; dst = convWb; doff = g;
        if (g < 147456)      { src = c3W; off = g; }
        else if (g < 221184) { src = c2W; off = g - 147456; }
        else if (g < 258048) { src = c1W; off = g - 221184; }
        else if (g < 276480) { src = c0W; off = g - 258048; }
        else                 { src = hW;  off = g - 276480; }
    }
    float4 v = *(const float4*)(src + off);
    g4u u;
    u.h[0] = (__bf16)v.x; u.h[1] = (__bf16)v.y; u.h[2] = (__bf16)v.z; u.h[3] = (__bf16)v.w;
    *(unsigned long long*)(dst + doff) = u.q;
}

// ---------------------------------------------------------------------------
// Fused LSTM, grid = 18 x 512 (8 waves/WG -> 2 waves/EU -> 256 reg budget):
//  bid 0..15 : Phase-A WGs (dir=bid>>3, sub=bid&7): 128 gate-rows x 64 t.
//              wave = m-tile, 4 t-tiles per wave.
//  bid 16,17 : recurrence WGs (dir=bid-16), one CU each:
//              wf[8][4] i32x4 = 128 VGPRs of int8 Whh, register-resident.
//              h int8 in LDS ping-pong; z history staged in LDS (zst),
//              flushed once per layer -> NO global stores in the step loop.
//              Lanes ln<8 own one cell each: cell = wave*32 + ln*4 + quad.
// m = cell*4 + gate everywhere; weight row r = gate*256 + cell.
// ---------------------------------------------------------------------------
__global__ __launch_bounds__(512) __attribute__((amdgpu_waves_per_eu(2, 2)))
void lstm_fused(
    const float* __restrict__ audio,
    const __bf16* __restrict__ WihB,
    const signed char* __restrict__ WhhQ,
    const float* __restrict__ swp,
    const float* __restrict__ b0, const float* __restrict__ bL,
    unsigned short* __restrict__ Gx_g,  // [2][64][1024] bf16 bits
    unsigned int* __restrict__ flags,
    unsigned short* __restrict__ zbuf)  // [2][64][512] bf16 bits
{
    const int bid = blockIdx.x;
    const int tid = threadIdx.x;
    const int wave = tid >> 6, lane = tid & 63, ln = lane & 15, quad = lane >> 4;

    __shared__ __align__(16) signed char  hq[2][256];
    __shared__ __align__(16) unsigned short zst[64][256];

    if (bid < 16) {
        // ---------------- Phase A ----------------
        const int dir = bid >> 3, sub = bid & 7;
        const int gmt = sub * 8 + wave;          // global m-tile 0..63
        for (int l = 0; l < 5; ++l) {
            if (l > 0) {
                if (tid == 0) {
                    while (ld_rlx(&flags[128 + (l - 1) * 2 + 0]) == 0) __builtin_amdgcn_s_sleep(8);
                    while (ld_rlx(&flags[128 + (l - 1) * 2 + 1]) == 0) __builtin_amdgcn_s_sleep(8);
                    (void)__hip_atomic_load(&flags[128 + (l - 1) * 2], __ATOMIC_ACQUIRE, SCOPE_AGENT);
                }
                __syncthreads();
            }
            const int Din = l ? 512 : 768;
            const __bf16* Wih_l = l ? (WihB + O_WIHL + (size_t)((l - 1) * 2 + dir) * 524288)
                                    : (WihB + (size_t)dir * 786432);
            const float* b_l = l ? (bL + (size_t)((l - 1) * 2 + dir) * 1024)
                                 : (b0 + (size_t)dir * 1024);
            const __bf16* zp = (const __bf16*)(zbuf + (size_t)((l - 1) & 1) * 32768);

            f32x4 acc[4];
            #pragma unroll
            for (int nt = 0; nt < 4; ++nt) acc[nt] = (f32x4){0.f, 0.f, 0.f, 0.f};
            const int m_a = gmt * 16 + ln;
            const int r_a = (m_a & 3) * 256 + (m_a >> 2);
            const int Kc = Din >> 5;
            for (int kc = 0; kc < Kc; ++kc) {
                const int k0 = kc * 32 + quad * 8;
                bf16x8 afr = *(const bf16x8*)(Wih_l + (size_t)r_a * Din + k0);
                #pragma unroll
                for (int nt = 0; nt < 4; ++nt) {
                    const int t = nt * 16 + ln;
                    bf16x8 bfr = l ? *(const bf16x8*)(zp + (size_t)t * 512 + k0)
                                   : cvt8(audio + (size_t)t * 768 + k0);
                    acc[nt] = mfma16(afr, bfr, acc[nt]);
                }
            }
            float bv[4];
            #pragma unroll
            for (int reg = 0; reg < 4; ++reg) {
                const int m_row = gmt * 16 + quad * 4 + reg;
                bv[reg] = b_l[(m_row & 3) * 256 + (m_row >> 2)];
            }
            #pragma unroll
            for (int nt = 0; nt < 4; ++nt) {
                #pragma unroll
                for (int reg = 0; reg < 4; ++reg) {
                    const int m_row = gmt * 16 + quad * 4 + reg;
                    const int t = nt * 16 + ln;
                    __bf16 v = (__bf16)(acc[nt][reg] + bv[reg]);
                    Gx_g[(size_t)dir * 65536 + t * 1024 + m_row] =
                        __builtin_bit_cast(unsigned short, v);
                }
            }
            __syncthreads();
            if (tid == 0) {
                __threadfence();
                __hip_atomic_store(&flags[l * 16 + bid], 1u, __ATOMIC_RELEASE, SCOPE_AGENT);
            }
        }
    } else {
        // ---------------- recurrence ----------------
        const int dir = bid - 16;
        const unsigned short* Gx_d = Gx_g + (size_t)dir * 65536;
        const bool owner = (ln < 8);
        const int cell = wave * 32 + ln * 4 + quad;   // valid when owner

        for (int l = 0; l < 5; ++l) {
            const int dl = l * 2 + dir;
            // register-resident int8 Whh (loads overlap the Phase-A wait)
            i32x4 wf[8][4];
            const i32x4* wb = (const i32x4*)(WhhQ + (size_t)dl * 262144);
            #pragma unroll
            for (int i = 0; i < 8; ++i)
                #pragma unroll
                for (int kc = 0; kc < 4; ++kc)
                    wf[i][kc] = wb[(size_t)(((wave * 8 + i) * 4 + kc)) * 64 + lane];
            float sc0 = 0.f, sc1 = 0.f, sc2 = 0.f, sc3 = 0.f;
            if (owner) {
                float4 s4 = *(const float4*)(swp + (size_t)dl * 1024 + cell * 4);
                const float f = 1.f / 127.f;
                sc0 = s4.x * f; sc1 = s4.y * f; sc2 = s4.z * f; sc3 = s4.w * f;
            }
            if (tid == 0) {
                for (int w = 0; w < 8; ++w)
                    while (ld_rlx(&flags[l * 16 + dir * 8 + w]) == 0) __builtin_amdgcn_s_sleep(8);
                (void)__hip_atomic_load(&flags[l * 16 + dir * 8], __ATOMIC_ACQUIRE, SCOPE_AGENT);
            }
            if (tid < 64) ((unsigned int*)hq[0])[tid] = 0;
            float cst = 0.f;
            __syncthreads();

            for (int s = 0; s < 64; ++s) {
                const int t = dir ? (63 - s) : s;
                const int cur = s & 1, nxt = cur ^ 1;
                g4u gx; gx.q = 0;
                if (owner) gx.q = *(const unsigned long long*)(Gx_d + (size_t)t * 1024 + cell * 4);
                i32x4 acc[8];
                #pragma unroll
                for (int i = 0; i < 8; ++i) acc[i] = (i32x4){0, 0, 0, 0};
                #pragma unroll
                for (int kc = 0; kc < 4; ++kc) {
                    i32x4 b = *(const i32x4*)&hq[cur][kc * 64 + quad * 16];
                    #pragma unroll
                    for (int i = 0; i < 8; ++i) acc[i] = mfma_i8(wf[i][kc], b, acc[i]);
                }
                i32x4 a = acc[0];
                #pragma unroll
                for (int j = 1; j < 8; ++j) if (ln == j) a = acc[j];
                if (owner) {
                    float gi = (float)a[0] * sc0 + (float)gx.h[0];
                    float gf = (float)a[1] * sc1 + (float)gx.h[1];
                    float gg = (float)a[2] * sc2 + (float)gx.h[2];
                    float go = (float)a[3] * sc3 + (float)gx.h[3];
                    cst = sigm(gf) * cst + sigm(gi) * tanh_(gg);
                    float h = sigm(go) * tanh_(cst);
                    hq[nxt][cell] = (signed char)__float2int_rn(h * 127.f);
                    zst[t][cell] = __builtin_bit_cast(unsigned short, (__bf16)h);
                }
                __syncthreads();
            }
            // flush staged z (32 KB) to global once per layer
            unsigned short* zl = zbuf + (size_t)(l & 1) * 32768;
            #pragma unroll
            for (int i = 0; i < 8; ++i) {
                const int idx = i * 512 + tid;
                const int tt = idx >> 6, c8 = idx & 63;
                *(unsigned long long*)(zl + (size_t)tt * 512 + dir * 256 + c8 * 4) =
                    *(const unsigned long long*)&zst[tt][c8 * 4];
            }
            __syncthreads();
            if (tid == 0) {
                __threadfence();
                __hip_atomic_store(&flags[128 + l * 2 + dir], 1u, __ATOMIC_RELEASE, SCOPE_AGENT);
            }
        }
    }
}

// ---------------------------------------------------------------------------
// fc: zb[64,512]bf16 @ Wb[2560,512]bf16 -> x4b [20][64][128] bf16. Grid = 40.
// ---------------------------------------------------------------------------
__global__ __launch_bounds__(256) void fc_kernel(
    const __bf16* __restrict__ zb, const __bf16* __restrict__ W,
    const float* __restrict__ bb, __bf16* __restrict__ out)
{
    const int tid = threadIdx.x;
    const int wave = tid >> 6, lane = tid & 63, ln = lane & 15, quad = lane >> 4;
    const int nbase = blockIdx.x * 64;
    f32x4 acc[4];
    #pragma unroll
    for (int nt = 0; nt < 4; nt++) acc[nt] = (f32x4){0.f, 0.f, 0.f, 0.f};
    #pragma unroll 2
    for (int kc = 0; kc < 16; kc++) {
        const int k0 = kc * 32 + quad * 8;
        bf16x8 a = *(const bf16x8*)(zb + (size_t)(wave * 16 + ln) * 512 + k0);
        #pragma unroll
        for (int nt = 0; nt < 4; nt++) {
            bf16x8 b = *(const bf16x8*)(W + (size_t)(nbase + nt * 16 + ln) * 512 + k0);
            acc[nt] = mfma16(a, b, acc[nt]);
        }
    }
    #pragma unroll
    for (int nt = 0; nt < 4; nt++) {
        const int n = nbase + nt * 16 + ln;
        const float bv = bb[n];
        #pragma unroll
        for (int reg = 0; reg < 4; reg++) {
            const int t = wave * 16 + quad * 4 + reg;
            out[(size_t)((n >> 7) * 64 + t) * 128 + (n & 127)] = (__bf16)(acc[nt][reg] + bv);
        }
    }
}

// ---------------------------------------------------------------------------
// pool: out[r][t][:] = sum_{s=0..2} vals[3r+s] * in[cols[3r+s]][t][:]
// ---------------------------------------------------------------------------
template <int C>
__global__ __launch_bounds__(256) void pool_kernel(
    const __bf16* __restrict__ in, __bf16* __restrict__ out,
    const int* __restrict__ cols, const float* __restrict__ vals, int V)
{
    const int P = 64 * C / 8;
    const int gid = blockIdx.x * 256 + threadIdx.x;
    if (gid >= V * P) return;
    const int r = gid / P;
    const int rem = gid - r * P;
    float acc[8] = {0.f, 0.f, 0.f, 0.f, 0.f, 0.f, 0.f, 0.f};
    #pragma unroll
    for (int s = 0; s < 3; s++) {
        const int col = cols[3 * r + s];
        const float vv = vals[3 * r + s];
        bf16x8 x = *(const bf16x8*)(in + (size_t)col * 64 * C + rem * 8);
        #pragma unroll
        for (int e = 0; e < 8; e++) acc[e] += vv * (float)x[e];
    }
    bf16x8 ov;
    #pragma unroll
    for (int e = 0; e < 8; e++) ov[e] = (__bf16)acc[e];
    *(bf16x8*)(out + (size_t)r * 64 * C + rem * 8) = ov;
}

// ---------------------------------------------------------------------------
// spiral conv + ELU: one vertex per block. in [Vin][64][CIN] bf16,
// W [COUT][9*CIN] bf16, out [V][64][COUT] bf16.
// ---------------------------------------------------------------------------
template <int CIN, int COUT>
__global__ __launch_bounds__(256) void conv_kernel(
    const __bf16* __restrict__ in, __bf16* __restrict__ out,
    const int* __restrict__ idx, const __bf16* __restrict__ W,
    const float* __restrict__ bias)
{
    constexpr int K = 9 * CIN;
    constexpr int NT = COUT / 16;
    constexpr int NKC = K / 32;
    const int v = blockIdx.x;
    const int tid = threadIdx.x;
    const int wave = tid >> 6, lane = tid & 63, ln = lane & 15, quad = lane >> 4;
    __shared__ int sIdx[9];
    if (tid < 9) sIdx[tid] = idx[v * 9 + tid];
    __syncthreads();
    f32x4 acc[NT];
    #pragma unroll
    for (int nt = 0; nt < NT; nt++) acc[nt] = (f32x4){0.f, 0.f, 0.f, 0.f};
    const int tt = wave * 16 + ln;
    for (int kc = 0; kc < NKC; kc++) {
        const int k0 = kc * 32;
        const int l = k0 / CIN;
        const int c = (k0 & (CIN - 1)) + quad * 8;
        const int row = sIdx[l];
        bf16x8 a = *(const bf16x8*)(in + ((size_t)row * 64 + tt) * CIN + c);
        #pragma unroll
        for (int nt = 0; nt < NT; nt++) {
            bf16x8 b = *(const bf16x8*)(W + (size_t)(nt * 16 + ln) * K + k0 + quad * 8);
            acc[nt] = mfma16(a, b, acc[nt]);
        }
    }
    #pragma unroll
    for (int nt = 0; nt < NT; nt++) {
        const int n = nt * 16 + ln;
        const float bv = bias[n];
        #pragma unroll
        for (int reg = 0; reg < 4; reg++) {
            const int t = wave * 16 + quad * 4 + reg;
            float val = acc[nt][reg] + bv;
            val = val > 0.f ? val : (__expf(val) - 1.f);   // ELU
            out[((size_t)v * 64 + t) * COUT + n] = (__bf16)val;
        }
    }
}

// ---------------------------------------------------------------------------
// head: spiral conv to 3 ch + actor offset -> [64][5023][3] f32
// ---------------------------------------------------------------------------
__global__ __launch_bounds__(256) void head_kernel(
    const __bf16* __restrict__ in, float* __restrict__ out,
    const int* __restrict__ idx, const __bf16* __restrict__ W,
    const float* __restrict__ bias, const float* __restrict__ actor)
{
    const int v = blockIdx.x;
    const int tid = threadIdx.x;
    const int wave = tid >> 6, lane = tid & 63, ln = lane & 15, quad = lane >> 4;
    __shared__ int sIdx[9];
    if (tid < 9) sIdx[tid] = idx[v * 9 + tid];
    __syncthreads();
    f32x4 acc = (f32x4){0.f, 0.f, 0.f, 0.f};
    const int tt = wave * 16 + ln;
    const int rown = ln < 3 ? ln : 0;
    #pragma unroll
    for (int kc = 0; kc < 9; kc++) {
        const int row = sIdx[kc];
        bf16x8 a = *(const bf16x8*)(in + ((size_t)row * 64 + tt) * 32 + quad * 8);
        bf16x8 b = *(const bf16x8*)(W + (size_t)rown * 288 + kc * 32 + quad * 8);
        acc = mfma16(a, b, acc);
    }
    if (ln < 3) {
        const float bv = bias[ln];
        const float av = actor[v * 3 + ln];
        #pragma unroll
        for (int reg = 0; reg < 4; reg++) {
            const int t = wave * 16 + quad * 4 + reg;
            out[((size_t)t * 5023 + v) * 3 + ln] = acc[reg] + bv + av;
        }
    }
}

extern "C" void kernel_launch(void* const* d_in, const int* in_sizes, int n_in,
                              void* d_out, int out_size, void* d_ws, size_t ws_size,
                              hipStream_t stream) {
    const float* audio = (const float*)d_in[0];
    const float* actor = (const float*)d_in[1];
    const float* Wih0  = (const float*)d_in[2];
    const float* Whh0  = (const float*)d_in[3];
    const float* b0    = (const float*)d_in[4];
    const float* WihL  = (const float*)d_in[5];
    const float* WhhL  = (const float*)d_in[6];
    const float* bLs   = (const float*)d_in[7];
    const float* fcW   = (const float*)d_in[8];
    const float* fcb   = (const float*)d_in[9];
    const float* c3W = (const float*)d_in[10]; const float* c3b = (const float*)d_in[11];
    const float* c2W = (const float*)d_in[12]; const float* c2b = (const float*)d_in[13];
    const float* c1W = (const float*)d_in[14]; const float* c1b = (const float*)d_in[15];
    const float* c0W = (const float*)d_in[16]; const float* c0b = (const float*)d_in[17];
    const float* hW  = (const float*)d_in[18]; const float* hb  = (const float*)d_in[19];
    const int* idx0 = (const int*)d_in[20];
    const int* idx1 = (const int*)d_in[21];
    const int* idx2 = (const int*)d_in[22];
    const int* idx3 = (const int*)d_in[23];
    const int* cols0 = (const int*)d_in[25]; const float* vals0 = (const float*)d_in[26];
    const int* cols1 = (const int*)d_in[28]; const float* vals1 = (const float*)d_in[29];
    const int* cols2 = (const int*)d_in[31]; const float* vals2 = (const float*)d_in[32];
    const int* cols3 = (const int*)d_in[34]; const float* vals3 = (const float*)d_in[35];

    char* ws = (char*)d_ws;
    unsigned int*   flags = (unsigned int*)ws;
    unsigned short* zbuf  = (unsigned short*)(ws + ZBUF_OFF);
    unsigned short* GxG   = (unsigned short*)(ws + GX_OFF);
    __bf16*         convWb = (__bf16*)(ws + CONVW_OFF);
    char* arenaA = ws + ARENA_A;
    char* arenaB = ws + ARENA_B;

    __bf16*      lw   = (__bf16*)arenaB;                      // Wih bf16
    signed char* whhq = (signed char*)(arenaB + WHHQ_BOFF);   // Whh int8
    float*       swp  = (float*)(arenaB + SWP_BOFF);          // row scales
    __bf16*      fcWb = (__bf16*)(arenaB + 2097152);          // dead after fc

    __bf16* x4b = (__bf16*)arenaA;   // [20][64][128]
    __bf16* p3  = (__bf16*)arenaB;   // [79][64][128]
    __bf16* c3o = (__bf16*)arenaA;   // [79][64][128]
    __bf16* p2  = (__bf16*)arenaB;   // [314][64][128]
    __bf16* c2o = (__bf16*)arenaA;   // [314][64][64]
    __bf16* p1  = (__bf16*)arenaB;   // [1256][64][64]
    __bf16* c1o = (__bf16*)arenaA;   // [1256][64][64]
    __bf16* p0  = (__bf16*)arenaB;   // [5023][64][64]
    __bf16* c0o = (__bf16*)arenaA;   // [5023][64][32]

    hipMemsetAsync(ws, 0, 1024, stream);   // flags

    precvt_lstm<<<5632, 256, 0, stream>>>(Wih0, WihL, lw);
    precvt_whhq<<<10240, 64, 0, stream>>>(Whh0, WhhL, whhq, swp);
    lstm_fused<<<18, 512, 0, stream>>>(audio, lw, whhq, swp, b0, bLs,
                                       GxG, flags, zbuf);
    precvt_dec<<<1552, 256, 0, stream>>>(fcW, c3W, c2W, c1W, c0W, hW, fcWb, convWb);

    fc_kernel<<<40, 256, 0, stream>>>((const __bf16*)zbuf, fcWb, fcb, x4b);

    { int n = 79 * 64 * 128 / 8;
      pool_kernel<128><<<(n + 255) / 256, 256, 0, stream>>>(x4b, p3, cols3, vals3, 79);
      conv_kernel<128, 128><<<79, 256, 0, stream>>>(p3, c3o, idx3, convWb + 0, c3b); }
    { int n = 314 * 64 * 128 / 8;
      pool_kernel<128><<<(n + 255) / 256, 256, 0, stream>>>(c3o, p2, cols2, vals2, 314);
      conv_kernel<128, 64><<<314, 256, 0, stream>>>(p2, c2o, idx2, convWb + 147456, c2b); }
    { int n = 1256 * 64 * 64 / 8;
      pool_kernel<64><<<(n + 255) / 256, 256, 0, stream>>>(c2o, p1, cols1, vals1, 1256);
      conv_kernel<64, 64><<<1256, 256, 0, stream>>>(p1, c1o, idx1, convWb + 221184, c1b); }
    { int n = 5023 * 64 * 64 / 8;
      pool_kernel<64><<<(n + 255) / 256, 256, 0, stream>>>(c1o, p0, cols0, vals0, 5023);
      conv_kernel<64, 32><<<5023, 256, 0, stream>>>(p0, c0o, idx0, convWb + 258048, c0b); }

    head_kernel<<<5023, 256, 0, stream>>>(c0o, (float*)d_out, idx0, convWb + 276480, hb, actor);
}

// Round 8
// 958.385 us; speedup vs baseline: 3.4404x; 1.0900x over previous
//
#include <hip/hip_runtime.h>
#include <hip/hip_bf16.h>

typedef __attribute__((ext_vector_type(8))) __bf16 bf16x8;
typedef __attribute__((ext_vector_type(4))) float  f32x4;
typedef __attribute__((ext_vector_type(4))) int    i32x4;

#define SCOPE_AGENT __HIP_MEMORY_SCOPE_AGENT

static __device__ __forceinline__ f32x4 mfma16(bf16x8 a, bf16x8 b, f32x4 c) {
    return __builtin_amdgcn_mfma_f32_16x16x32_bf16(a, b, c, 0, 0, 0);
}
static __device__ __forceinline__ i32x4 mfma_i8(i32x4 a, i32x4 b, i32x4 c) {
    return __builtin_amdgcn_mfma_i32_16x16x64_i8(a, b, c, 0, 0, 0);
}
static __device__ __forceinline__ float sigm(float x)  { return 1.0f / (1.0f + __expf(-x)); }
static __device__ __forceinline__ float tanh_(float x) { return 1.0f - 2.0f / (__expf(2.0f * x) + 1.0f); }

static __device__ __forceinline__ bf16x8 cvt8(const float* __restrict__ p) {
    const float4* q = (const float4*)p;
    float4 a = q[0], b = q[1];
    bf16x8 r;
    r[0] = (__bf16)a.x; r[1] = (__bf16)a.y; r[2] = (__bf16)a.z; r[3] = (__bf16)a.w;
    r[4] = (__bf16)b.x; r[5] = (__bf16)b.y; r[6] = (__bf16)b.z; r[7] = (__bf16)b.w;
    return r;
}
static __device__ __forceinline__ void signal_add(unsigned int* p) {
    __hip_atomic_fetch_add(p, 1u, __ATOMIC_RELEASE, SCOPE_AGENT);
}
template <int SLP>
static __device__ __forceinline__ void wait_eq(unsigned int* p, unsigned int v) {
    while (__hip_atomic_load(p, __ATOMIC_RELAXED, SCOPE_AGENT) != v)
        __builtin_amdgcn_s_sleep(SLP);
    (void)__hip_atomic_load(p, __ATOMIC_ACQUIRE, SCOPE_AGENT);
}
union g4u { unsigned long long q; __bf16 h[4]; };

// ---------------------------------------------------------------------------
// ws layout (bytes):
//   0        flags (1024, zeroed): pa_cnt @ u32[l*2+dir] (==8 when PA l,dir done)
//                                   z_cnt @ u32[32+l]     (==2 when both dirs done)
//   1024     zbuf  [2][64][512] bf16 = 131072   (zbuf0 survives -> fc)
//   132096   Gx_g  [2][64][1024] bf16 = 262144  (dead after lstm)
//   66560    convWb overlay (554688) over zbuf1+Gx, written after lstm
//   621248   arenaA (20,574,208)
//   21195456 arenaB: Wih bf16 @0; WhhQ i8 @11,534,336; swp @14,155,776;
//            fcWb @2,097,152 (written after lstm, dead after fc)
// ---------------------------------------------------------------------------
#define ZBUF_OFF   1024
#define GX_OFF     132096
#define CONVW_OFF  66560
#define ARENA_A    621248
#define ARENA_B    21195456
#define WHHQ_BOFF  11534336
#define SWP_BOFF   14155776
#define O_WIH0  0            // [2][1024][768]
#define O_WIHL  1572864      // [4][2][1024][512]

// ---------------------------------------------------------------------------
// one-time LSTM weight prep (merged): bid<5632 -> Wih f32->bf16 copy;
// bid>=5632 -> Whh per-row int8 quant into A-fragment order + scales.
// ---------------------------------------------------------------------------
__global__ __launch_bounds__(256) void precvt_lstm(
    const float* __restrict__ Wih0, const float* __restrict__ WihL,
    const float* __restrict__ Whh0, const float* __restrict__ WhhL,
    __bf16* __restrict__ out, signed char* __restrict__ WhhQ,
    float* __restrict__ swp)
{
    const int bid = blockIdx.x;
    if (bid < 5632) {
        int f = (bid * 256 + threadIdx.x) * 4;
        const float* src; int off;
        if (f < 1572864) { src = Wih0; off = f; }
        else             { src = WihL; off = f - 1572864; }
        float4 v = *(const float4*)(src + off);
        g4u u;
        u.h[0] = (__bf16)v.x; u.h[1] = (__bf16)v.y; u.h[2] = (__bf16)v.z; u.h[3] = (__bf16)v.w;
        *(unsigned long long*)(out + f) = u.q;
        return;
    }
    // Whh quant: one wave per (dl, row r)
    const int g  = (bid - 5632) * 4 + (threadIdx.x >> 6);   // 0..10239
    const int dl = g >> 10;
    const int r  = g & 1023;
    const int lane = threadIdx.x & 63;
    const float* src = (dl < 2 ? Whh0 + (size_t)dl * 262144
                               : WhhL + (size_t)(dl - 2) * 262144) + (size_t)r * 256;
    float4 v = *(const float4*)(src + lane * 4);
    float am = fmaxf(fmaxf(fabsf(v.x), fabsf(v.y)), fmaxf(fabsf(v.z), fabsf(v.w)));
    #pragma unroll
    for (int m = 1; m < 64; m <<= 1) am = fmaxf(am, __shfl_xor(am, m));
    const float inv = am > 0.f ? 127.f / am : 0.f;
    int q0 = __float2int_rn(v.x * inv), q1 = __float2int_rn(v.y * inv);
    int q2 = __float2int_rn(v.z * inv), q3 = __float2int_rn(v.w * inv);
    unsigned pk = (q0 & 255) | ((q1 & 255) << 8) | ((q2 & 255) << 16) | ((q3 & 255) << 24);
    const int gate = r >> 8, cell = r & 255;
    const int m  = cell * 4 + gate;
    const int ln = m & 15, mt = m >> 4;
    const int k  = lane * 4;
    const int kc = k >> 6, quad = (k >> 4) & 3, j = k & 15;
    size_t addr = ((((size_t)dl * 64 + mt) * 4 + kc) * 64 + (quad * 16 + ln)) * 16 + j;
    *(unsigned*)(WhhQ + addr) = pk;
    if (lane == 0) swp[(size_t)dl * 1024 + cell * 4 + gate] = am / 127.f;
}

// decoder weights f32->bf16 (after lstm; convWb overlays dead lstm buffers)
__global__ __launch_bounds__(256) void precvt_dec(
    const float* __restrict__ fcW, const float* __restrict__ c3W,
    const float* __restrict__ c2W, const float* __restrict__ c1W,
    const float* __restrict__ c0W, const float* __restrict__ hW,
    __bf16* __restrict__ fcWb, __bf16* __restrict__ convWb)
{
    int f = (blockIdx.x * 256 + threadIdx.x) * 4;
    if (f >= 1588064) return;
    const float* src; int off; __bf16* dst; int doff;
    if (f < 1310720) { src = fcW; off = f; dst = fcWb; doff = f; }
    else {
        int g = f - 1310720; dst = convWb; doff = g;
        if (g < 147456)      { src = c3W; off = g; }
        else if (g < 221184) { src = c2W; off = g - 147456; }
        else if (g < 258048) { src = c1W; off = g - 221184; }
        else if (g < 276480) { src = c0W; off = g - 258048; }
        else                 { src = hW;  off = g - 276480; }
    }
    float4 v = *(const float4*)(src + off);
    g4u u;
    u.h[0] = (__bf16)v.x; u.h[1] = (__bf16)v.y; u.h[2] = (__bf16)v.z; u.h[3] = (__bf16)v.w;
    *(unsigned long long*)(dst + doff) = u.q;
}

// ---------------------------------------------------------------------------
// Fused LSTM, grid = 18 x 512 (8 waves/WG -> 2 waves/EU -> 256 reg budget):
//  bid 0..15 : Phase-A WGs (dir=bid>>3, sub=bid&7): Gx = Wih@x + b.
//  bid 16,17 : recurrence WGs (dir=bid-16), one CU each:
//    wf[8][4] i32x4 = 128 regs of int8 Whh, register-resident.
//    Per layer: Gx staged into LDS (128 KB burst) -> step loop touches NO
//    global memory. h int8 LDS ping-pong; z history int8 in LDS, flushed
//    (dequant->bf16) once per layer. One __syncthreads per step.
// m = cell*4 + gate everywhere; weight row r = gate*256 + cell.
// ---------------------------------------------------------------------------
__global__ __launch_bounds__(512) __attribute__((amdgpu_waves_per_eu(2, 2)))
void lstm_fused(
    const float* __restrict__ audio,
    const __bf16* __restrict__ WihB,
    const signed char* __restrict__ WhhQ,
    const float* __restrict__ swp,
    const float* __restrict__ b0, const float* __restrict__ bL,
    unsigned short* __restrict__ Gx_g,  // [2][64][1024] bf16 bits
    unsigned int* __restrict__ flags,
    unsigned short* __restrict__ zbuf)  // [2][64][512] bf16 bits
{
    const int bid = blockIdx.x;
    const int tid = threadIdx.x;
    const int wave = tid >> 6, lane = tid & 63, ln = lane & 15, quad = lane >> 4;

    __shared__ __align__(16) signed char    hq[2][256];
    __shared__ __align__(16) signed char    zq[16384];        // [t][cell] i8
    __shared__ __align__(16) unsigned short gx_l[65536];      // [t][1024] bf16 bits

    if (bid < 16) {
        // ---------------- Phase A ----------------
        const int dir = bid >> 3, sub = bid & 7;
        const int gmt = sub * 8 + wave;          // global m-tile 0..63
        for (int l = 0; l < 5; ++l) {
            if (l > 0) {
                if (tid == 0) wait_eq<4>(&flags[32 + (l - 1)], 2u);
                __syncthreads();
            }
            const int Din = l ? 512 : 768;
            const __bf16* Wih_l = l ? (WihB + O_WIHL + (size_t)((l - 1) * 2 + dir) * 524288)
                                    : (WihB + (size_t)dir * 786432);
            const float* b_l = l ? (bL + (size_t)((l - 1) * 2 + dir) * 1024)
                                 : (b0 + (size_t)dir * 1024);
            const __bf16* zp = (const __bf16*)(zbuf + (size_t)((l - 1) & 1) * 32768);

            f32x4 acc[4];
            #pragma unroll
            for (int nt = 0; nt < 4; ++nt) acc[nt] = (f32x4){0.f, 0.f, 0.f, 0.f};
            const int m_a = gmt * 16 + ln;
            const int r_a = (m_a & 3) * 256 + (m_a >> 2);
            const int Kc = Din >> 5;
            for (int kc = 0; kc < Kc; ++kc) {
                const int k0 = kc * 32 + quad * 8;
                bf16x8 afr = *(const bf16x8*)(Wih_l + (size_t)r_a * Din + k0);
                #pragma unroll
                for (int nt = 0; nt < 4; ++nt) {
                    const int t = nt * 16 + ln;
                    bf16x8 bfr = l ? *(const bf16x8*)(zp + (size_t)t * 512 + k0)
                                   : cvt8(audio + (size_t)t * 768 + k0);
                    acc[nt] = mfma16(afr, bfr, acc[nt]);
                }
            }
            float bv[4];
            #pragma unroll
            for (int reg = 0; reg < 4; ++reg) {
                const int m_row = gmt * 16 + quad * 4 + reg;
                bv[reg] = b_l[(m_row & 3) * 256 + (m_row >> 2)];
            }
            #pragma unroll
            for (int nt = 0; nt < 4; ++nt) {
                #pragma unroll
                for (int reg = 0; reg < 4; ++reg) {
                    const int m_row = gmt * 16 + quad * 4 + reg;
                    const int t = nt * 16 + ln;
                    __bf16 v = (__bf16)(acc[nt][reg] + bv[reg]);
                    Gx_g[(size_t)dir * 65536 + t * 1024 + m_row] =
                        __builtin_bit_cast(unsigned short, v);
                }
            }
            __syncthreads();
            if (tid == 0) { __threadfence(); signal_add(&flags[l * 2 + dir]); }
        }
    } else {
        // ---------------- recurrence ----------------
        const int dir = bid - 16;
        const unsigned short* Gx_d = Gx_g + (size_t)dir * 65536;
        const bool owner = (ln < 8);
        const int cell = wave * 32 + ln * 4 + quad;   // valid when owner
        const int gcell = owner ? cell : 0;

        for (int l = 0; l < 5; ++l) {
            const int dl = l * 2 + dir;
            // register-resident int8 Whh (loads overlap the Phase-A wait)
            i32x4 wf[8][4];
            const i32x4* wb = (const i32x4*)(WhhQ + (size_t)dl * 262144);
            #pragma unroll
            for (int i = 0; i < 8; ++i)
                #pragma unroll
                for (int kc = 0; kc < 4; ++kc)
                    wf[i][kc] = wb[(size_t)(((wave * 8 + i) * 4 + kc)) * 64 + lane];
            float sc0 = 0.f, sc1 = 0.f, sc2 = 0.f, sc3 = 0.f;
            if (owner) {
                float4 s4 = *(const float4*)(swp + (size_t)dl * 1024 + cell * 4);
                const float f = 1.f / 127.f;
                sc0 = s4.x * f; sc1 = s4.y * f; sc2 = s4.z * f; sc3 = s4.w * f;
            }
            if (tid == 0) wait_eq<1>(&flags[l * 2 + dir], 8u);
            __syncthreads();
            // stage this layer's Gx into LDS (128 KB burst)
            {
                const float4* src = (const float4*)Gx_d;
                float4* dst = (float4*)gx_l;
                #pragma unroll
                for (int i = 0; i < 16; ++i) dst[i * 512 + tid] = src[i * 512 + tid];
            }
            if (tid < 64) ((unsigned int*)hq[0])[tid] = 0;
            float cst = 0.f;
            __syncthreads();

            for (int s = 0; s < 64; ++s) {
                const int t = dir ? (63 - s) : s;
                const int cur = s & 1, nxt = cur ^ 1;
                // early, unconditional LDS read of this step's gate bias
                g4u gx;
                gx.q = *(const unsigned long long*)&gx_l[t * 1024 + gcell * 4];
                i32x4 acc[8];
                #pragma unroll
                for (int i = 0; i < 8; ++i) acc[i] = (i32x4){0, 0, 0, 0};
                #pragma unroll
                for (int kc = 0; kc < 4; ++kc) {
                    i32x4 b = *(const i32x4*)&hq[cur][kc * 64 + quad * 16];
                    #pragma unroll
                    for (int i = 0; i < 8; ++i) acc[i] = mfma_i8(wf[i][kc], b, acc[i]);
                }
                i32x4 a = acc[0];
                #pragma unroll
                for (int j = 1; j < 8; ++j) if (ln == j) a = acc[j];
                if (owner) {
                    float gi = (float)a[0] * sc0 + (float)gx.h[0];
                    float gf = (float)a[1] * sc1 + (float)gx.h[1];
                    float gg = (float)a[2] * sc2 + (float)gx.h[2];
                    float go = (float)a[3] * sc3 + (float)gx.h[3];
                    cst = sigm(gf) * cst + sigm(gi) * tanh_(gg);
                    float h = sigm(go) * tanh_(cst);
                    int q = __float2int_rn(h * 127.f);
                    hq[nxt][cell] = (signed char)q;
                    zq[t * 256 + cell] = (signed char)q;
                }
                __syncthreads();
            }
            // flush z history (i8 -> bf16) to global, once per layer
            unsigned short* zl = zbuf + (size_t)(l & 1) * 32768;
            #pragma unroll
            for (int i = 0; i < 8; ++i) {
                const int idx = i * 512 + tid;      // dword index 0..4095
                const int tt = idx >> 6, cb = (idx & 63) * 4;
                unsigned u = ((const unsigned*)zq)[idx];
                g4u o;
                #pragma unroll
                for (int j = 0; j < 4; ++j) {
                    int b = (int)(signed char)(u >> (8 * j));
                    o.h[j] = (__bf16)((float)b * (1.f / 127.f));
                }
                *(unsigned long long*)(zl + (size_t)tt * 512 + dir * 256 + cb) = o.q;
            }
            __syncthreads();
            if (tid == 0) { __threadfence(); signal_add(&flags[32 + l]); }
        }
    }
}

// ---------------------------------------------------------------------------
// fc: zb[64,512]bf16 @ Wb[2560,512]bf16 -> x4b [20][64][128] bf16. Grid = 40.
// ---------------------------------------------------------------------------
__global__ __launch_bounds__(256) void fc_kernel(
    const __bf16* __restrict__ zb, const __bf16* __restrict__ W,
    const float* __restrict__ bb, __bf16* __restrict__ out)
{
    const int tid = threadIdx.x;
    const int wave = tid >> 6, lane = tid & 63, ln = lane & 15, quad = lane >> 4;
    const int nbase = blockIdx.x * 64;
    f32x4 acc[4];
    #pragma unroll
    for (int nt = 0; nt < 4; nt++) acc[nt] = (f32x4){0.f, 0.f, 0.f, 0.f};
    #pragma unroll 2
    for (int kc = 0; kc < 16; kc++) {
        const int k0 = kc * 32 + quad * 8;
        bf16x8 a = *(const bf16x8*)(zb + (size_t)(wave * 16 + ln) * 512 + k0);
        #pragma unroll
        for (int nt = 0; nt < 4; nt++) {
            bf16x8 b = *(const bf16x8*)(W + (size_t)(nbase + nt * 16 + ln) * 512 + k0);
            acc[nt] = mfma16(a, b, acc[nt]);
        }
    }
    #pragma unroll
    for (int nt = 0; nt < 4; nt++) {
        const int n = nbase + nt * 16 + ln;
        const float bv = bb[n];
        #pragma unroll
        for (int reg = 0; reg < 4; reg++) {
            const int t = wave * 16 + quad * 4 + reg;
            out[(size_t)((n >> 7) * 64 + t) * 128 + (n & 127)] = (__bf16)(acc[nt][reg] + bv);
        }
    }
}

// ---------------------------------------------------------------------------
// pool: out[r][t][:] = sum_{s=0..2} vals[3r+s] * in[cols[3r+s]][t][:]
// ---------------------------------------------------------------------------
template <int C>
__global__ __launch_bounds__(256) void pool_kernel(
    const __bf16* __restrict__ in, __bf16* __restrict__ out,
    const int* __restrict__ cols, const float* __restrict__ vals, int V)
{
    const int P = 64 * C / 8;
    const int gid = blockIdx.x * 256 + threadIdx.x;
    if (gid >= V * P) return;
    const int r = gid / P;
    const int rem = gid - r * P;
    float acc[8] = {0.f, 0.f, 0.f, 0.f, 0.f, 0.f, 0.f, 0.f};
    #pragma unroll
    for (int s = 0; s < 3; s++) {
        const int col = cols[3 * r + s];
        const float vv = vals[3 * r + s];
        bf16x8 x = *(const bf16x8*)(in + (size_t)col * 64 * C + rem * 8);
        #pragma unroll
        for (int e = 0; e < 8; e++) acc[e] += vv * (float)x[e];
    }
    bf16x8 ov;
    #pragma unroll
    for (int e = 0; e < 8; e++) ov[e] = (__bf16)acc[e];
    *(bf16x8*)(out + (size_t)r * 64 * C + rem * 8) = ov;
}

// ---------------------------------------------------------------------------
// spiral conv + ELU: one vertex per block. in [Vin][64][CIN] bf16,
// W [COUT][9*CIN] bf16, out [V][64][COUT] bf16.
// ---------------------------------------------------------------------------
template <int CIN, int COUT>
__global__ __launch_bounds__(256) void conv_kernel(
    const __bf16* __restrict__ in, __bf16* __restrict__ out,
    const int* __restrict__ idx, const __bf16* __restrict__ W,
    const float* __restrict__ bias)
{
    constexpr int K = 9 * CIN;
    constexpr int NT = COUT / 16;
    constexpr int NKC = K / 32;
    const int v = blockIdx.x;
    const int tid = threadIdx.x;
    const int wave = tid >> 6, lane = tid & 63, ln = lane & 15, quad = lane >> 4;
    __shared__ int sIdx[9];
    if (tid < 9) sIdx[tid] = idx[v * 9 + tid];
    __syncthreads();
    f32x4 acc[NT];
    #pragma unroll
    for (int nt = 0; nt < NT; nt++) acc[nt] = (f32x4){0.f, 0.f, 0.f, 0.f};
    const int tt = wave * 16 + ln;
    for (int kc = 0; kc < NKC; kc++) {
        const int k0 = kc * 32;
        const int l = k0 / CIN;
        const int c = (k0 & (CIN - 1)) + quad * 8;
        const int row = sIdx[l];
        bf16x8 a = *(const bf16x8*)(in + ((size_t)row * 64 + tt) * CIN + c);
        #pragma unroll
        for (int nt = 0; nt < NT; nt++) {
            bf16x8 b = *(const bf16x8*)(W + (size_t)(nt * 16 + ln) * K + k0 + quad * 8);
            acc[nt] = mfma16(a, b, acc[nt]);
        }
    }
    #pragma unroll
    for (int nt = 0; nt < NT; nt++) {
        const int n = nt * 16 + ln;
        const float bv = bias[n];
        #pragma unroll
        for (int reg = 0; reg < 4; reg++) {
            const int t = wave * 16 + quad * 4 + reg;
            float val = acc[nt][reg] + bv;
            val = val > 0.f ? val : (__expf(val) - 1.f);   // ELU
            out[((size_t)v * 64 + t) * COUT + n] = (__bf16)val;
        }
    }
}

// ---------------------------------------------------------------------------
// head: spiral conv to 3 ch + actor offset -> [64][5023][3] f32
// ---------------------------------------------------------------------------
__global__ __launch_bounds__(256) void head_kernel(
    const __bf16* __restrict__ in, float* __restrict__ out,
    const int* __restrict__ idx, const __bf16* __restrict__ W,
    const float* __restrict__ bias, const float* __restrict__ actor)
{
    const int v = blockIdx.x;
    const int tid = threadIdx.x;
    const int wave = tid >> 6, lane = tid & 63, ln = lane & 15, quad = lane >> 4;
    __shared__ int sIdx[9];
    if (tid < 9) sIdx[tid] = idx[v * 9 + tid];
    __syncthreads();
    f32x4 acc = (f32x4){0.f, 0.f, 0.f, 0.f};
    const int tt = wave * 16 + ln;
    const int rown = ln < 3 ? ln : 0;
    #pragma unroll
    for (int kc = 0; kc < 9; kc++) {
        const int row = sIdx[kc];
        bf16x8 a = *(const bf16x8*)(in + ((size_t)row * 64 + tt) * 32 + quad * 8);
        bf16x8 b = *(const bf16x8*)(W + (size_t)rown * 288 + kc * 32 + quad * 8);
        acc = mfma16(a, b, acc);
    }
    if (ln < 3) {
        const float bv = bias[ln];
        const float av = actor[v * 3 + ln];
        #pragma unroll
        for (int reg = 0; reg < 4; reg++) {
            const int t = wave * 16 + quad * 4 + reg;
            out[((size_t)t * 5023 + v) * 3 + ln] = acc[reg] + bv + av;
        }
    }
}

extern "C" void kernel_launch(void* const* d_in, const int* in_sizes, int n_in,
                              void* d_out, int out_size, void* d_ws, size_t ws_size,
                              hipStream_t stream) {
    const float* audio = (const float*)d_in[0];
    const float* actor = (const float*)d_in[1];
    const float* Wih0  = (const float*)d_in[2];
    const float* Whh0  = (const float*)d_in[3];
    const float* b0    = (const float*)d_in[4];
    const float* WihL  = (const float*)d_in[5];
    const float* WhhL  = (const float*)d_in[6];
    const float* bLs   = (const float*)d_in[7];
    const float* fcW   = (const float*)d_in[8];
    const float* fcb   = (const float*)d_in[9];
    const float* c3W = (const float*)d_in[10]; const float* c3b = (const float*)d_in[11];
    const float* c2W = (const float*)d_in[12]; const float* c2b = (const float*)d_in[13];
    const float* c1W = (const float*)d_in[14]; const float* c1b = (const float*)d_in[15];
    const float* c0W = (const float*)d_in[16]; const float* c0b = (const float*)d_in[17];
    const float* hW  = (const float*)d_in[18]; const float* hb  = (const float*)d_in[19];
    const int* idx0 = (const int*)d_in[20];
    const int* idx1 = (const int*)d_in[21];
    const int* idx2 = (const int*)d_in[22];
    const int* idx3 = (const int*)d_in[23];
    const int* cols0 = (const int*)d_in[25]; const float* vals0 = (const float*)d_in[26];
    const int* cols1 = (const int*)d_in[28]; const float* vals1 = (const float*)d_in[29];
    const int* cols2 = (const int*)d_in[31]; const float* vals2 = (const float*)d_in[32];
    const int* cols3 = (const int*)d_in[34]; const float* vals3 = (const float*)d_in[35];

    char* ws = (char*)d_ws;
    unsigned int*   flags = (unsigned int*)ws;
    unsigned short* zbuf  = (unsigned short*)(ws + ZBUF_OFF);
    unsigned short* GxG   = (unsigned short*)(ws + GX_OFF);
    __bf16*         convWb = (__bf16*)(ws + CONVW_OFF);
    char* arenaA = ws + ARENA_A;
    char* arenaB = ws + ARENA_B;

    __bf16*      lw   = (__bf16*)arenaB;                      // Wih bf16
    signed char* whhq = (signed char*)(arenaB + WHHQ_BOFF);   // Whh int8
    float*       swp  = (float*)(arenaB + SWP_BOFF);          // row scales
    __bf16*      fcWb = (__bf16*)(arenaB + 2097152);          // dead after fc

    __bf16* x4b = (__bf16*)arenaA;   // [20][64][128]
    __bf16* p3  = (__bf16*)arenaB;   // [79][64][128]
    __bf16* c3o = (__bf16*)arenaA;   // [79][64][128]
    __bf16* p2  = (__bf16*)arenaB;   // [314][64][128]
    __bf16* c2o = (__bf16*)arenaA;   // [314][64][64]
    __bf16* p1  = (__bf16*)arenaB;   // [1256][64][64]
    __bf16* c1o = (__bf16*)arenaA;   // [1256][64][64]
    __bf16* p0  = (__bf16*)arenaB;   // [5023][64][64]
    __bf16* c0o = (__bf16*)arenaA;   // [5023][64][32]

    (void)hipMemsetAsync(ws, 0, 1024, stream);   // flags

    precvt_lstm<<<8192, 256, 0, stream>>>(Wih0, WihL, Whh0, WhhL, lw, whhq, swp);
    lstm_fused<<<18, 512, 0, stream>>>(audio, lw, whhq, swp, b0, bLs,
                                       GxG, flags, zbuf);
    precvt_dec<<<1552, 256, 0, stream>>>(fcW, c3W, c2W, c1W, c0W, hW, fcWb, convWb);

    fc_kernel<<<40, 256, 0, stream>>>((const __bf16*)zbuf, fcWb, fcb, x4b);

    { int n = 79 * 64 * 128 / 8;
      pool_kernel<128><<<(n + 255) / 256, 256, 0, stream>>>(x4b, p3, cols3, vals3, 79);
      conv_kernel<128, 128><<<79, 256, 0, stream>>>(p3, c3o, idx3, convWb + 0, c3b); }
    { int n = 314 * 64 * 128 / 8;
      pool_kernel<128><<<(n + 255) / 256, 256, 0, stream>>>(c3o, p2, cols2, vals2, 314);
      conv_kernel<128, 64><<<314, 256, 0, stream>>>(p2, c2o, idx2, convWb + 147456, c2b); }
    { int n = 1256 * 64 * 64 / 8;
      pool_kernel<64><<<(n + 255) / 256, 256, 0, stream>>>(c2o, p1, cols1, vals1, 1256);
      conv_kernel<64, 64><<<1256, 256, 0, stream>>>(p1, c1o, idx1, convWb + 221184, c1b); }
    { int n = 5023 * 64 * 64 / 8;
      pool_kernel<64><<<(n + 255) / 256, 256, 0, stream>>>(c1o, p0, cols0, vals0, 5023);
      conv_kernel<64, 32><<<5023, 256, 0, stream>>>(p0, c0o, idx0, convWb + 258048, c0b); }

    head_kernel<<<5023, 256, 0, stream>>>(c0o, (float*)d_out, idx0, convWb + 276480, hb, actor);
}

// Round 9
// 949.896 us; speedup vs baseline: 3.4711x; 1.0089x over previous
//
#include <hip/hip_runtime.h>
#include <hip/hip_bf16.h>

typedef __attribute__((ext_vector_type(8))) __bf16 bf16x8;
typedef __attribute__((ext_vector_type(4))) float  f32x4;
typedef __attribute__((ext_vector_type(4))) int    i32x4;

#define SCOPE_AGENT __HIP_MEMORY_SCOPE_AGENT

static __device__ __forceinline__ f32x4 mfma16(bf16x8 a, bf16x8 b, f32x4 c) {
    return __builtin_amdgcn_mfma_f32_16x16x32_bf16(a, b, c, 0, 0, 0);
}
static __device__ __forceinline__ i32x4 mfma_i8(i32x4 a, i32x4 b, i32x4 c) {
    return __builtin_amdgcn_mfma_i32_16x16x64_i8(a, b, c, 0, 0, 0);
}
static __device__ __forceinline__ float sigm(float x)  { return 1.0f / (1.0f + __expf(-x)); }
static __device__ __forceinline__ float tanh_(float x) { return 1.0f - 2.0f / (__expf(2.0f * x) + 1.0f); }

static __device__ __forceinline__ bf16x8 cvt8(const float* __restrict__ p) {
    const float4* q = (const float4*)p;
    float4 a = q[0], b = q[1];
    bf16x8 r;
    r[0] = (__bf16)a.x; r[1] = (__bf16)a.y; r[2] = (__bf16)a.z; r[3] = (__bf16)a.w;
    r[4] = (__bf16)b.x; r[5] = (__bf16)b.y; r[6] = (__bf16)b.z; r[7] = (__bf16)b.w;
    return r;
}
static __device__ __forceinline__ void signal_add(unsigned int* p) {
    __hip_atomic_fetch_add(p, 1u, __ATOMIC_RELEASE, SCOPE_AGENT);
}
template <int SLP>
static __device__ __forceinline__ void wait_eq(unsigned int* p, unsigned int v) {
    while (__hip_atomic_load(p, __ATOMIC_RELAXED, SCOPE_AGENT) != v)
        __builtin_amdgcn_s_sleep(SLP);
    (void)__hip_atomic_load(p, __ATOMIC_ACQUIRE, SCOPE_AGENT);
}
union g4u { unsigned long long q; __bf16 h[4]; };

// ---------------------------------------------------------------------------
// ws layout (bytes):
//   0        flags (1024, zeroed): pa_cnt @ u32[l*2+dir] (==8 when PA l,dir done)
//                                   z_cnt @ u32[32+l]     (==2 when both dirs done)
//   1024     zbuf  [2][64][512] bf16 = 131072   (zbuf0 survives -> fc)
//   132096   Gx_g  [2][64][1024] bf16 = 262144  (dead after lstm)
//   66560    convWb overlay (554688) over zbuf1+Gx, written after lstm
//   621248   arenaA (20,574,208)
//   21195456 arenaB: WhhQ i8 @11,534,336; swp @14,155,776;
//            fcWb @2,097,152 (written after lstm, dead after fc)
// ---------------------------------------------------------------------------
#define ZBUF_OFF   1024
#define GX_OFF     132096
#define CONVW_OFF  66560
#define ARENA_A    621248
#define ARENA_B    21195456
#define WHHQ_BOFF  11534336
#define SWP_BOFF   14155776

// ---------------------------------------------------------------------------
// one-time: Whh -> per-row-absmax int8 in A-fragment order + scales.
// One wave per (dl, row r). r = gate*256 + cell; m = cell*4 + gate.
// ---------------------------------------------------------------------------
__global__ __launch_bounds__(256) void precvt_whh(
    const float* __restrict__ Whh0, const float* __restrict__ WhhL,
    signed char* __restrict__ WhhQ, float* __restrict__ swp)
{
    const int g  = blockIdx.x * 4 + (threadIdx.x >> 6);   // 0..10239
    const int dl = g >> 10;
    const int r  = g & 1023;
    const int lane = threadIdx.x & 63;
    const float* src = (dl < 2 ? Whh0 + (size_t)dl * 262144
                               : WhhL + (size_t)(dl - 2) * 262144) + (size_t)r * 256;
    float4 v = *(const float4*)(src + lane * 4);
    float am = fmaxf(fmaxf(fabsf(v.x), fabsf(v.y)), fmaxf(fabsf(v.z), fabsf(v.w)));
    #pragma unroll
    for (int m = 1; m < 64; m <<= 1) am = fmaxf(am, __shfl_xor(am, m));
    const float inv = am > 0.f ? 127.f / am : 0.f;
    int q0 = __float2int_rn(v.x * inv), q1 = __float2int_rn(v.y * inv);
    int q2 = __float2int_rn(v.z * inv), q3 = __float2int_rn(v.w * inv);
    unsigned pk = (q0 & 255) | ((q1 & 255) << 8) | ((q2 & 255) << 16) | ((q3 & 255) << 24);
    const int gate = r >> 8, cell = r & 255;
    const int m  = cell * 4 + gate;
    const int ln = m & 15, mt = m >> 4;
    const int k  = lane * 4;
    const int kc = k >> 6, quad = (k >> 4) & 3, j = k & 15;
    size_t addr = ((((size_t)dl * 64 + mt) * 4 + kc) * 64 + (quad * 16 + ln)) * 16 + j;
    *(unsigned*)(WhhQ + addr) = pk;
    if (lane == 0) swp[(size_t)dl * 1024 + cell * 4 + gate] = am / 127.f;
}

// decoder weights f32->bf16 (after lstm; convWb overlays dead lstm buffers)
__global__ __launch_bounds__(256) void precvt_dec(
    const float* __restrict__ fcW, const float* __restrict__ c3W,
    const float* __restrict__ c2W, const float* __restrict__ c1W,
    const float* __restrict__ c0W, const float* __restrict__ hW,
    __bf16* __restrict__ fcWb, __bf16* __restrict__ convWb)
{
    int f = (blockIdx.x * 256 + threadIdx.x) * 4;
    if (f >= 1588064) return;
    const float* src; int off; __bf16* dst; int doff;
    if (f < 1310720) { src = fcW; off = f; dst = fcWb; doff = f; }
    else {
        int g = f - 1310720; dst = convWb; doff = g;
        if (g < 147456)      { src = c3W; off = g; }
        else if (g < 221184) { src = c2W; off = g - 147456; }
        else if (g < 258048) { src = c1W; off = g - 221184; }
        else if (g < 276480) { src = c0W; off = g - 258048; }
        else                 { src = hW;  off = g - 276480; }
    }
    float4 v = *(const float4*)(src + off);
    g4u u;
    u.h[0] = (__bf16)v.x; u.h[1] = (__bf16)v.y; u.h[2] = (__bf16)v.z; u.h[3] = (__bf16)v.w;
    *(unsigned long long*)(dst + doff) = u.q;
}

// ---------------------------------------------------------------------------
// Fused LSTM, grid = 18 x 512 (8 waves/WG -> 2 waves/EU -> 256 reg budget):
//  bid 0..15 : Phase-A WGs (dir=bid>>3, sub=bid&7): Gx = Wih@x + b.
//    Wih read DIRECTLY from f32 inputs (cvt on the fly). Layers 1-4 prefetch
//    the whole row-fragment (afr[16] = 64 VGPRs) BEFORE the z-wait, so the
//    weight stream overlaps the previous layer's recurrence.
//  bid 16,17 : recurrence WGs (dir=bid-16), one CU each:
//    wf[8][4] i32x4 = 128 regs of int8 Whh, register-resident. Gx staged to
//    LDS per layer; step loop touches NO global memory. czero = persistent
//    zero C-operand (no per-step acc zero-init).
// m = cell*4 + gate everywhere; weight row r = gate*256 + cell.
// ---------------------------------------------------------------------------
__global__ __launch_bounds__(512) __attribute__((amdgpu_waves_per_eu(2, 2)))
void lstm_fused(
    const float* __restrict__ audio,
    const float* __restrict__ Wih0,     // [2][1024][768] f32
    const float* __restrict__ WihL,     // [4][2][1024][512] f32
    const signed char* __restrict__ WhhQ,
    const float* __restrict__ swp,
    const float* __restrict__ b0, const float* __restrict__ bL,
    unsigned short* __restrict__ Gx_g,  // [2][64][1024] bf16 bits
    unsigned int* __restrict__ flags,
    unsigned short* __restrict__ zbuf)  // [2][64][512] bf16 bits
{
    const int bid = blockIdx.x;
    const int tid = threadIdx.x;
    const int wave = tid >> 6, lane = tid & 63, ln = lane & 15, quad = lane >> 4;

    __shared__ __align__(16) signed char    hq[2][256];
    __shared__ __align__(16) signed char    zq[16384];        // [t][cell] i8
    __shared__ __align__(16) unsigned short gx_l[65536];      // [t][1024] bf16 bits

    if (bid < 16) {
        // ---------------- Phase A ----------------
        const int dir = bid >> 3, sub = bid & 7;
        const int gmt = sub * 8 + wave;          // global m-tile 0..63
        const int m_a = gmt * 16 + ln;
        const int r_a = (m_a & 3) * 256 + (m_a >> 2);

        // ---- layer 0 (no wait; stream Wih f32 directly) ----
        {
            const float* Wih_l = Wih0 + (size_t)dir * 786432;
            const float* b_l   = b0 + (size_t)dir * 1024;
            f32x4 acc[4];
            #pragma unroll
            for (int nt = 0; nt < 4; ++nt) acc[nt] = (f32x4){0.f, 0.f, 0.f, 0.f};
            for (int kc = 0; kc < 24; ++kc) {
                const int k0 = kc * 32 + quad * 8;
                bf16x8 afr = cvt8(Wih_l + (size_t)r_a * 768 + k0);
                #pragma unroll
                for (int nt = 0; nt < 4; ++nt) {
                    const int t = nt * 16 + ln;
                    bf16x8 bfr = cvt8(audio + (size_t)t * 768 + k0);
                    acc[nt] = mfma16(afr, bfr, acc[nt]);
                }
            }
            float bv[4];
            #pragma unroll
            for (int reg = 0; reg < 4; ++reg) {
                const int m_row = gmt * 16 + quad * 4 + reg;
                bv[reg] = b_l[(m_row & 3) * 256 + (m_row >> 2)];
            }
            #pragma unroll
            for (int nt = 0; nt < 4; ++nt)
                #pragma unroll
                for (int reg = 0; reg < 4; ++reg) {
                    const int m_row = gmt * 16 + quad * 4 + reg;
                    const int t = nt * 16 + ln;
                    __bf16 v = (__bf16)(acc[nt][reg] + bv[reg]);
                    Gx_g[(size_t)dir * 65536 + t * 1024 + m_row] =
                        __builtin_bit_cast(unsigned short, v);
                }
            __syncthreads();
            if (tid == 0) { __threadfence(); signal_add(&flags[0 * 2 + dir]); }
        }

        // ---- layers 1-4: prefetch Wih fragment into regs, THEN wait ----
        for (int l = 1; l < 5; ++l) {
            const float* Wih_l = WihL + (size_t)((l - 1) * 2 + dir) * 524288;
            const float* b_l   = bL + (size_t)((l - 1) * 2 + dir) * 1024;
            bf16x8 afr[16];
            #pragma unroll
            for (int kc = 0; kc < 16; ++kc)
                afr[kc] = cvt8(Wih_l + (size_t)r_a * 512 + kc * 32 + quad * 8);
            if (tid == 0) wait_eq<4>(&flags[32 + (l - 1)], 2u);
            __syncthreads();
            const __bf16* zp = (const __bf16*)(zbuf + (size_t)((l - 1) & 1) * 32768);

            f32x4 acc[4];
            #pragma unroll
            for (int nt = 0; nt < 4; ++nt) acc[nt] = (f32x4){0.f, 0.f, 0.f, 0.f};
            #pragma unroll 4
            for (int kc = 0; kc < 16; ++kc) {
                const int k0 = kc * 32 + quad * 8;
                #pragma unroll
                for (int nt = 0; nt < 4; ++nt) {
                    const int t = nt * 16 + ln;
                    bf16x8 bfr = *(const bf16x8*)(zp + (size_t)t * 512 + k0);
                    acc[nt] = mfma16(afr[kc], bfr, acc[nt]);
                }
            }
            float bv[4];
            #pragma unroll
            for (int reg = 0; reg < 4; ++reg) {
                const int m_row = gmt * 16 + quad * 4 + reg;
                bv[reg] = b_l[(m_row & 3) * 256 + (m_row >> 2)];
            }
            #pragma unroll
            for (int nt = 0; nt < 4; ++nt)
                #pragma unroll
                for (int reg = 0; reg < 4; ++reg) {
                    const int m_row = gmt * 16 + quad * 4 + reg;
                    const int t = nt * 16 + ln;
                    __bf16 v = (__bf16)(acc[nt][reg] + bv[reg]);
                    Gx_g[(size_t)dir * 65536 + t * 1024 + m_row] =
                        __builtin_bit_cast(unsigned short, v);
                }
            __syncthreads();
            if (tid == 0) { __threadfence(); signal_add(&flags[l * 2 + dir]); }
        }
    } else {
        // ---------------- recurrence ----------------
        const int dir = bid - 16;
        const unsigned short* Gx_d = Gx_g + (size_t)dir * 65536;
        const bool owner = (ln < 8);
        const int cell = wave * 32 + ln * 4 + quad;   // valid when owner
        const int gcell = owner ? cell : 0;
        const i32x4 czero = (i32x4){0, 0, 0, 0};

        for (int l = 0; l < 5; ++l) {
            const int dl = l * 2 + dir;
            // register-resident int8 Whh (loads overlap the Phase-A wait)
            i32x4 wf[8][4];
            const i32x4* wb = (const i32x4*)(WhhQ + (size_t)dl * 262144);
            #pragma unroll
            for (int i = 0; i < 8; ++i)
                #pragma unroll
                for (int kc = 0; kc < 4; ++kc)
                    wf[i][kc] = wb[(size_t)(((wave * 8 + i) * 4 + kc)) * 64 + lane];
            float sc0 = 0.f, sc1 = 0.f, sc2 = 0.f, sc3 = 0.f;
            if (owner) {
                float4 s4 = *(const float4*)(swp + (size_t)dl * 1024 + cell * 4);
                const float f = 1.f / 127.f;
                sc0 = s4.x * f; sc1 = s4.y * f; sc2 = s4.z * f; sc3 = s4.w * f;
            }
            if (tid == 0) wait_eq<1>(&flags[l * 2 + dir], 8u);
            __syncthreads();
            // stage this layer's Gx into LDS (128 KB burst)
            {
                const float4* src = (const float4*)Gx_d;
                float4* dst = (float4*)gx_l;
                #pragma unroll
                for (int i = 0; i < 16; ++i) dst[i * 512 + tid] = src[i * 512 + tid];
            }
            if (tid < 64) ((unsigned int*)hq[0])[tid] = 0;
            float cst = 0.f;
            __syncthreads();

            for (int s = 0; s < 64; ++s) {
                const int t = dir ? (63 - s) : s;
                const int cur = s & 1, nxt = cur ^ 1;
                // early, unconditional LDS read of this step's gate bias
                g4u gx;
                gx.q = *(const unsigned long long*)&gx_l[t * 1024 + gcell * 4];
                i32x4 acc[8];
                {
                    i32x4 b0v = *(const i32x4*)&hq[cur][quad * 16];
                    #pragma unroll
                    for (int i = 0; i < 8; ++i) acc[i] = mfma_i8(wf[i][0], b0v, czero);
                }
                #pragma unroll
                for (int kc = 1; kc < 4; ++kc) {
                    i32x4 b = *(const i32x4*)&hq[cur][kc * 64 + quad * 16];
                    #pragma unroll
                    for (int i = 0; i < 8; ++i) acc[i] = mfma_i8(wf[i][kc], b, acc[i]);
                }
                i32x4 a = acc[0];
                #pragma unroll
                for (int j = 1; j < 8; ++j) if (ln == j) a = acc[j];
                if (owner) {
                    float gi = (float)a[0] * sc0 + (float)gx.h[0];
                    float gf = (float)a[1] * sc1 + (float)gx.h[1];
                    float gg = (float)a[2] * sc2 + (float)gx.h[2];
                    float go = (float)a[3] * sc3 + (float)gx.h[3];
                    cst = sigm(gf) * cst + sigm(gi) * tanh_(gg);
                    float h = sigm(go) * tanh_(cst);
                    int q = __float2int_rn(h * 127.f);
                    hq[nxt][cell] = (signed char)q;
                    zq[t * 256 + cell] = (signed char)q;
                }
                __syncthreads();
            }
            // flush z history (i8 -> bf16) to global, once per layer
            unsigned short* zl = zbuf + (size_t)(l & 1) * 32768;
            #pragma unroll
            for (int i = 0; i < 8; ++i) {
                const int idx = i * 512 + tid;      // dword index 0..4095
                const int tt = idx >> 6, cb = (idx & 63) * 4;
                unsigned u = ((const unsigned*)zq)[idx];
                g4u o;
                #pragma unroll
                for (int j = 0; j < 4; ++j) {
                    int b = (int)(signed char)(u >> (8 * j));
                    o.h[j] = (__bf16)((float)b * (1.f / 127.f));
                }
                *(unsigned long long*)(zl + (size_t)tt * 512 + dir * 256 + cb) = o.q;
            }
            __syncthreads();
            if (tid == 0) { __threadfence(); signal_add(&flags[32 + l]); }
        }
    }
}

// ---------------------------------------------------------------------------
// fc: zb[64,512]bf16 @ Wb[2560,512]bf16 -> x4b [20][64][128] bf16. Grid = 40.
// ---------------------------------------------------------------------------
__global__ __launch_bounds__(256) void fc_kernel(
    const __bf16* __restrict__ zb, const __bf16* __restrict__ W,
    const float* __restrict__ bb, __bf16* __restrict__ out)
{
    const int tid = threadIdx.x;
    const int wave = tid >> 6, lane = tid & 63, ln = lane & 15, quad = lane >> 4;
    const int nbase = blockIdx.x * 64;
    f32x4 acc[4];
    #pragma unroll
    for (int nt = 0; nt < 4; nt++) acc[nt] = (f32x4){0.f, 0.f, 0.f, 0.f};
    #pragma unroll 2
    for (int kc = 0; kc < 16; kc++) {
        const int k0 = kc * 32 + quad * 8;
        bf16x8 a = *(const bf16x8*)(zb + (size_t)(wave * 16 + ln) * 512 + k0);
        #pragma unroll
        for (int nt = 0; nt < 4; nt++) {
            bf16x8 b = *(const bf16x8*)(W + (size_t)(nbase + nt * 16 + ln) * 512 + k0);
            acc[nt] = mfma16(a, b, acc[nt]);
        }
    }
    #pragma unroll
    for (int nt = 0; nt < 4; nt++) {
        const int n = nbase + nt * 16 + ln;
        const float bv = bb[n];
        #pragma unroll
        for (int reg = 0; reg < 4; reg++) {
            const int t = wave * 16 + quad * 4 + reg;
            out[(size_t)((n >> 7) * 64 + t) * 128 + (n & 127)] = (__bf16)(acc[nt][reg] + bv);
        }
    }
}

// ---------------------------------------------------------------------------
// pool: out[r][t][:] = sum_{s=0..2} vals[3r+s] * in[cols[3r+s]][t][:]
// ---------------------------------------------------------------------------
template <int C>
__global__ __launch_bounds__(256) void pool_kernel(
    const __bf16* __restrict__ in, __bf16* __restrict__ out,
    const int* __restrict__ cols, const float* __restrict__ vals, int V)
{
    const int P = 64 * C / 8;
    const int gid = blockIdx.x * 256 + threadIdx.x;
    if (gid >= V * P) return;
    const int r = gid / P;
    const int rem = gid - r * P;
    float acc[8] = {0.f, 0.f, 0.f, 0.f, 0.f, 0.f, 0.f, 0.f};
    #pragma unroll
    for (int s = 0; s < 3; s++) {
        const int col = cols[3 * r + s];
        const float vv = vals[3 * r + s];
        bf16x8 x = *(const bf16x8*)(in + (size_t)col * 64 * C + rem * 8);
        #pragma unroll
        for (int e = 0; e < 8; e++) acc[e] += vv * (float)x[e];
    }
    bf16x8 ov;
    #pragma unroll
    for (int e = 0; e < 8; e++) ov[e] = (__bf16)acc[e];
    *(bf16x8*)(out + (size_t)r * 64 * C + rem * 8) = ov;
}

// ---------------------------------------------------------------------------
// spiral conv + ELU: one vertex per block. in [Vin][64][CIN] bf16,
// W [COUT][9*CIN] bf16, out [V][64][COUT] bf16.
// ---------------------------------------------------------------------------
template <int CIN, int COUT>
__global__ __launch_bounds__(256) void conv_kernel(
    const __bf16* __restrict__ in, __bf16* __restrict__ out,
    const int* __restrict__ idx, const __bf16* __restrict__ W,
    const float* __restrict__ bias)
{
    constexpr int K = 9 * CIN;
    constexpr int NT = COUT / 16;
    constexpr int NKC = K / 32;
    const int v = blockIdx.x;
    const int tid = threadIdx.x;
    const int wave = tid >> 6, lane = tid & 63, ln = lane & 15, quad = lane >> 4;
    __shared__ int sIdx[9];
    if (tid < 9) sIdx[tid] = idx[v * 9 + tid];
    __syncthreads();
    f32x4 acc[NT];
    #pragma unroll
    for (int nt = 0; nt < NT; nt++) acc[nt] = (f32x4){0.f, 0.f, 0.f, 0.f};
    const int tt = wave * 16 + ln;
    for (int kc = 0; kc < NKC; kc++) {
        const int k0 = kc * 32;
        const int l = k0 / CIN;
        const int c = (k0 & (CIN - 1)) + quad * 8;
        const int row = sIdx[l];
        bf16x8 a = *(const bf16x8*)(in + ((size_t)row * 64 + tt) * CIN + c);
        #pragma unroll
        for (int nt = 0; nt < NT; nt++) {
            bf16x8 b = *(const bf16x8*)(W + (size_t)(nt * 16 + ln) * K + k0 + quad * 8);
            acc[nt] = mfma16(a, b, acc[nt]);
        }
    }
    #pragma unroll
    for (int nt = 0; nt < NT; nt++) {
        const int n = nt * 16 + ln;
        const float bv = bias[n];
        #pragma unroll
        for (int reg = 0; reg < 4; reg++) {
            const int t = wave * 16 + quad * 4 + reg;
            float val = acc[nt][reg] + bv;
            val = val > 0.f ? val : (__expf(val) - 1.f);   // ELU
            out[((size_t)v * 64 + t) * COUT + n] = (__bf16)val;
        }
    }
}

// ---------------------------------------------------------------------------
// head: spiral conv to 3 ch + actor offset -> [64][5023][3] f32
// ---------------------------------------------------------------------------
__global__ __launch_bounds__(256) void head_kernel(
    const __bf16* __restrict__ in, float* __restrict__ out,
    const int* __restrict__ idx, const __bf16* __restrict__ W,
    const float* __restrict__ bias, const float* __restrict__ actor)
{
    const int v = blockIdx.x;
    const int tid = threadIdx.x;
    const int wave = tid >> 6, lane = tid & 63, ln = lane & 15, quad = lane >> 4;
    __shared__ int sIdx[9];
    if (tid < 9) sIdx[tid] = idx[v * 9 + tid];
    __syncthreads();
    f32x4 acc = (f32x4){0.f, 0.f, 0.f, 0.f};
    const int tt = wave * 16 + ln;
    const int rown = ln < 3 ? ln : 0;
    #pragma unroll
    for (int kc = 0; kc < 9; kc++) {
        const int row = sIdx[kc];
        bf16x8 a = *(const bf16x8*)(in + ((size_t)row * 64 + tt) * 32 + quad * 8);
        bf16x8 b = *(const bf16x8*)(W + (size_t)rown * 288 + kc * 32 + quad * 8);
        acc = mfma16(a, b, acc);
    }
    if (ln < 3) {
        const float bv = bias[ln];
        const float av = actor[v * 3 + ln];
        #pragma unroll
        for (int reg = 0; reg < 4; reg++) {
            const int t = wave * 16 + quad * 4 + reg;
            out[((size_t)t * 5023 + v) * 3 + ln] = acc[reg] + bv + av;
        }
    }
}

extern "C" void kernel_launch(void* const* d_in, const int* in_sizes, int n_in,
                              void* d_out, int out_size, void* d_ws, size_t ws_size,
                              hipStream_t stream) {
    const float* audio = (const float*)d_in[0];
    const float* actor = (const float*)d_in[1];
    const float* Wih0  = (const float*)d_in[2];
    const float* Whh0  = (const float*)d_in[3];
    const float* b0    = (const float*)d_in[4];
    const float* WihL  = (const float*)d_in[5];
    const float* WhhL  = (const float*)d_in[6];
    const float* bLs   = (const float*)d_in[7];
    const float* fcW   = (const float*)d_in[8];
    const float* fcb   = (const float*)d_in[9];
    const float* c3W = (const float*)d_in[10]; const float* c3b = (const float*)d_in[11];
    const float* c2W = (const float*)d_in[12]; const float* c2b = (const float*)d_in[13];
    const float* c1W = (const float*)d_in[14]; const float* c1b = (const float*)d_in[15];
    const float* c0W = (const float*)d_in[16]; const float* c0b = (const float*)d_in[17];
    const float* hW  = (const float*)d_in[18]; const float* hb  = (const float*)d_in[19];
    const int* idx0 = (const int*)d_in[20];
    const int* idx1 = (const int*)d_in[21];
    const int* idx2 = (const int*)d_in[22];
    const int* idx3 = (const int*)d_in[23];
    const int* cols0 = (const int*)d_in[25]; const float* vals0 = (const float*)d_in[26];
    const int* cols1 = (const int*)d_in[28]; const float* vals1 = (const float*)d_in[29];
    const int* cols2 = (const int*)d_in[31]; const float* vals2 = (const float*)d_in[32];
    const int* cols3 = (const int*)d_in[34]; const float* vals3 = (const float*)d_in[35];

    char* ws = (char*)d_ws;
    unsigned int*   flags = (unsigned int*)ws;
    unsigned short* zbuf  = (unsigned short*)(ws + ZBUF_OFF);
    unsigned short* GxG   = (unsigned short*)(ws + GX_OFF);
    __bf16*         convWb = (__bf16*)(ws + CONVW_OFF);
    char* arenaA = ws + ARENA_A;
    char* arenaB = ws + ARENA_B;

    signed char* whhq = (signed char*)(arenaB + WHHQ_BOFF);   // Whh int8
    float*       swp  = (float*)(arenaB + SWP_BOFF);          // row scales
    __bf16*      fcWb = (__bf16*)(arenaB + 2097152);          // dead after fc

    __bf16* x4b = (__bf16*)arenaA;   // [20][64][128]
    __bf16* p3  = (__bf16*)arenaB;   // [79][64][128]
    __bf16* c3o = (__bf16*)arenaA;   // [79][64][128]
    __bf16* p2  = (__bf16*)arenaB;   // [314][64][128]
    __bf16* c2o = (__bf16*)arenaA;   // [314][64][64]
    __bf16* p1  = (__bf16*)arenaB;   // [1256][64][64]
    __bf16* c1o = (__bf16*)arenaA;   // [1256][64][64]
    __bf16* p0  = (__bf16*)arenaB;   // [5023][64][64]
    __bf16* c0o = (__bf16*)arenaA;   // [5023][64][32]

    (void)hipMemsetAsync(ws, 0, 1024, stream);   // flags

    precvt_whh<<<2560, 256, 0, stream>>>(Whh0, WhhL, whhq, swp);
    lstm_fused<<<18, 512, 0, stream>>>(audio, Wih0, WihL, whhq, swp, b0, bLs,
                                       GxG, flags, zbuf);
    precvt_dec<<<1552, 256, 0, stream>>>(fcW, c3W, c2W, c1W, c0W, hW, fcWb, convWb);

    fc_kernel<<<40, 256, 0, stream>>>((const __bf16*)zbuf, fcWb, fcb, x4b);

    { int n = 79 * 64 * 128 / 8;
      pool_kernel<128><<<(n + 255) / 256, 256, 0, stream>>>(x4b, p3, cols3, vals3, 79);
      conv_kernel<128, 128><<<79, 256, 0, stream>>>(p3, c3o, idx3, convWb + 0, c3b); }
    { int n = 314 * 64 * 128 / 8;
      pool_kernel<128><<<(n + 255) / 256, 256, 0, stream>>>(c3o, p2, cols2, vals2, 314);
      conv_kernel<128, 64><<<314, 256, 0, stream>>>(p2, c2o, idx2, convWb + 147456, c2b); }
    { int n = 1256 * 64 * 64 / 8;
      pool_kernel<64><<<(n + 255) / 256, 256, 0, stream>>>(c2o, p1, cols1, vals1, 1256);
      conv_kernel<64, 64><<<1256, 256, 0, stream>>>(p1, c1o, idx1, convWb + 221184, c1b); }
    { int n = 5023 * 64 * 64 / 8;
      pool_kernel<64><<<(n + 255) / 256, 256, 0, stream>>>(c1o, p0, cols0, vals0, 5023);
      conv_kernel<64, 32><<<5023, 256, 0, stream>>>(p0, c0o, idx0, convWb + 258048, c0b); }

    head_kernel<<<5023, 256, 0, stream>>>(c0o, (float*)d_out, idx0, convWb + 276480, hb, actor);
}